// Round 5
// baseline (7794.267 us; speedup 1.0000x reference)
//
#include <hip/hip_runtime.h>

#define SEQ   2048
#define NM    8192        // SEQ*BATCH

typedef __attribute__((ext_vector_type(4))) float f4;
typedef __attribute__((ext_vector_type(8))) __bf16 bf16x8;

__device__ __forceinline__ float frcp(float x){ return __builtin_amdgcn_rcpf(x); }
__device__ __forceinline__ float sigm(float x){ return frcp(1.f + __expf(-x)); }
__device__ __forceinline__ float tanhf_(float x){ return 1.f - 2.f*frcp(__expf(2.f*x) + 1.f); }
__device__ __forceinline__ f4 sigm4(f4 x){
  f4 r; r.x = sigm(x.x); r.y = sigm(x.y); r.z = sigm(x.z); r.w = sigm(x.w); return r;
}
__device__ __forceinline__ f4 tanh4(f4 x){
  f4 r; r.x = tanhf_(x.x); r.y = tanhf_(x.y); r.z = tanhf_(x.z); r.w = tanhf_(x.w); return r;
}
__device__ __forceinline__ f4 mfma16(bf16x8 a, bf16x8 b, f4 c){
  return __builtin_amdgcn_mfma_f32_16x16x32_bf16(a, b, c, 0, 0, 0);
}
// LDS-only barrier: h-tile coherence needs lgkmcnt(0) only; G prefetch global
// loads stay in flight across the barrier.
__device__ __forceinline__ void barrier_lds_only(){
  asm volatile("s_waitcnt lgkmcnt(0)\n\ts_barrier" ::: "memory");
}

// ---------------------------------------------------------------------------
// Generic tiled GEMM: out = A[M,K] @ W[N,K]^T (+bias), optional epilogues.
// mode 0: plain   mode 1: softplus   mode 2: LSTM-G store [dir][t][j][b], time-
// reversed for dir1.  W1 != null => rows >= Nhalf come from W1.
// ---------------------------------------------------------------------------
__global__ __launch_bounds__(256) void gemm_k(
    const float* __restrict__ A, int lda,
    const float* __restrict__ W0, const float* __restrict__ W1, int Nhalf,
    const float* __restrict__ b0a, const float* __restrict__ b0b,
    const float* __restrict__ b1a, const float* __restrict__ b1b,
    float* __restrict__ out, int M, int N, int K, int mode)
{
  __shared__ float As[64][17];
  __shared__ float Ws[64][17];
  const int tid = threadIdx.x;
  const int tn = tid & 15, tm = tid >> 4;
  const int n0 = blockIdx.x * 64, m0 = blockIdx.y * 64;
  const int srow = tid >> 2, sk = (tid & 3) * 4;
  float acc[4][4] = {};
  for (int k0 = 0; k0 < K; k0 += 16) {
    const int am = m0 + srow;
    #pragma unroll
    for (int q = 0; q < 4; ++q) {
      int k = k0 + sk + q;
      As[srow][sk + q] = (k < K) ? A[(size_t)am * lda + k] : 0.f;
    }
    const int wn = n0 + srow;
    const float* Wp = W0; int nn = wn;
    if (W1 != nullptr && wn >= Nhalf) { Wp = W1; nn = wn - Nhalf; }
    #pragma unroll
    for (int q = 0; q < 4; ++q) {
      int k = k0 + sk + q;
      Ws[srow][sk + q] = (wn < N && k < K) ? Wp[(size_t)nn * K + k] : 0.f;
    }
    __syncthreads();
    #pragma unroll
    for (int k = 0; k < 16; ++k) {
      float a[4], w[4];
      #pragma unroll
      for (int i = 0; i < 4; ++i) a[i] = As[tm*4+i][k];
      #pragma unroll
      for (int j = 0; j < 4; ++j) w[j] = Ws[tn*4+j][k];
      #pragma unroll
      for (int i = 0; i < 4; ++i)
        #pragma unroll
        for (int j = 0; j < 4; ++j) acc[i][j] += a[i]*w[j];
    }
    __syncthreads();
  }
  #pragma unroll
  for (int i = 0; i < 4; ++i) {
    #pragma unroll
    for (int j = 0; j < 4; ++j) {
      int m = m0 + tm*4 + i, n = n0 + tn*4 + j;
      if (n >= N) continue;
      float bias = 0.f;
      if (n < Nhalf) { if (b0a) bias += b0a[n]; if (b0b) bias += b0b[n]; }
      else { if (b1a) bias += b1a[n - Nhalf]; if (b1b) bias += b1b[n - Nhalf]; }
      float v = acc[i][j] + bias;
      if (mode == 1) { v = (v > 15.f) ? v : __logf(1.f + __expf(v)); }
      if (mode == 2) {
        int dd = n >> 8, jj = n & 255, t = m >> 2, b = m & 3;
        int tq = dd ? (SEQ - 1 - t) : t;
        out[((size_t)(dd*SEQ + tq) * 256 + jj) * 4 + b] = v;
      } else {
        out[(size_t)m * N + n] = v;
      }
    }
  }
}

// causal depthwise conv (4 taps) + SiLU.  xz: [NM,512] (xi = cols 0..255)
__global__ __launch_bounds__(256) void conv_silu_k(
    const float* __restrict__ xz, const float* __restrict__ cw,
    const float* __restrict__ cb, float* __restrict__ xc)
{
  int idx = blockIdx.x * 256 + threadIdx.x;
  int d = idx & 255, m = idx >> 8;
  int t = m >> 2, b = m & 3;
  float s = cb[d];
  #pragma unroll
  for (int k = 0; k < 4; ++k) {
    int tt = t - 3 + k;
    if (tt >= 0) s += xz[(size_t)(tt*4 + b) * 512 + d] * cw[d*4 + k];
  }
  xc[idx] = s * sigm(s);
}

// selective scan: wave per (b,d), lane per state s.
__global__ __launch_bounds__(256) void mamba_scan_k(
    const float* __restrict__ dbc, const float* __restrict__ dtb,
    const float* __restrict__ xc, const float* __restrict__ Alog,
    float* __restrict__ ys)
{
  const int wid = blockIdx.x * 4 + (threadIdx.x >> 6);
  const int lane = threadIdx.x & 63;
  const int b = wid >> 8, d = wid & 255;
  const float Av = -__expf(Alog[d*64 + lane]);
  const float* pB  = dbc + (size_t)b*136 + 8 + lane;
  const float* pC  = dbc + (size_t)b*136 + 72 + lane;
  const float* pdt = dtb + (size_t)b*256 + d;
  const float* px  = xc  + (size_t)b*256 + d;
  float* py = ys + (size_t)b*256 + d;
  float h = 0.f;
  float Bv = pB[0], Cv = pC[0], dtv = pdt[0], xv = px[0];
  #pragma unroll 2
  for (int t = 0; t < SEQ; ++t) {
    float Bn = 0.f, Cn = 0.f, dtn = 0.f, xn = 0.f;
    if (t + 1 < SEQ) {
      size_t od = (size_t)(t+1) * 544;   // 4 rows * 136
      size_t ox = (size_t)(t+1) * 1024;  // 4 rows * 256
      Bn = pB[od]; Cn = pC[od]; dtn = pdt[ox]; xn = px[ox];
    }
    float a = __expf(dtv * Av);
    h = a*h + (dtv*xv)*Bv;
    float p = h * Cv;
    #pragma unroll
    for (int mm = 1; mm < 64; mm <<= 1) p += __shfl_xor(p, mm, 64);
    if (lane == 0) py[(size_t)t * 1024] = p;
    Bv = Bn; Cv = Cn; dtv = dtn; xv = xn;
  }
}

// y = (ys + xc*D) * silu(z)
__global__ __launch_bounds__(256) void ycomb_k(
    const float* __restrict__ xz, const float* __restrict__ ys,
    const float* __restrict__ xc, const float* __restrict__ Dsk,
    float* __restrict__ yc)
{
  int idx = blockIdx.x * 256 + threadIdx.x;
  int d = idx & 255, m = idx >> 8;
  float z = xz[(size_t)m * 512 + 256 + d];
  yc[idx] = (ys[idx] + xc[idx]*Dsk[d]) * z * sigm(z);
}

// ---------------------------------------------------------------------------
// LSTM recurrent scan, one block per direction, 4 waves (R2 structure, R2
// MFMA ordering restored — R4's chain split regressed via acc-init VALU).
// THIS ROUND'S single change vs R2: IN-LANE activations.  The C fragment of
// the 16x16x32 MFMA already gives lane l15 (rows 0-3 block) all 4 gates x
// 4 batches for hid unit w*16+l15 in registers a0..a3 (reg index = batch).
// So lanes 0-15 compute sigmoid/tanh/c/h as f4 over batches — the glds
// gate-redistribution LDS round-trip (~150-200 serial cyc/step) is gone.
// h is written back as 8 ds_write_u16 (hi/lo x 4 batches), out as 4 strided
// global stores.  Math per element is identical to R2 -> absmax unchanged.
// ---------------------------------------------------------------------------
#define HROW 80   // padded row stride (bf16)
__global__ __launch_bounds__(256, 1) void lstm_scan_k(
    const float* __restrict__ G,    // [2][SEQ][256][4]
    const float* __restrict__ Whh,  // [2][256][64] (layer base)
    float* __restrict__ out)        // [SEQ][4][128]
{
  const int dir = blockIdx.x;
  const int tid = threadIdx.x;
  const int w = tid >> 6, lane = tid & 63;
  const int l15 = lane & 15, q = lane >> 4;

  __shared__ __bf16 hb[2][2][16][HROW];   // [buf][hi/lo][m=batch][k=n]

  for (int i = tid; i < 2*2*16*HROW; i += 256) ((__bf16*)hb)[i] = (__bf16)0.f;

  const float* Gd = G + (size_t)dir * SEQ * 1024;
  const float* Wd = Whh + dir * 256 * 64;

  // B fragments (constant over t): wave w owns gate tiles {w, w+4, w+8, w+12}
  bf16x8 bh[4][2], bl[4][2];
  #pragma unroll
  for (int g4 = 0; g4 < 4; ++g4) {
    const int j = (g4*4 + w)*16 + l15;
    #pragma unroll
    for (int kt = 0; kt < 2; ++kt) {
      const float* src = Wd + j*64 + kt*32 + q*8;
      #pragma unroll
      for (int e = 0; e < 8; ++e) {
        float v = src[e];
        __bf16 hi = (__bf16)v;
        bh[g4][kt][e] = hi;
        bl[g4][kt][e] = (__bf16)(v - (float)hi);
      }
    }
  }

  f4 ccv = {0.f, 0.f, 0.f, 0.f};   // cell state, batches 0-3 (lanes 0-15 only)
  f4 gp0[4], gp1[4], gp2[4], gp3[4];

  auto loadG = [&](int t, f4* gv) {
    #pragma unroll
    for (int g4 = 0; g4 < 4; ++g4) {
      const int j = (g4*4 + w)*16 + l15;
      gv[g4] = *(const f4*)(Gd + ((size_t)t * 256 + j) * 4);  // [j][b0..b3]
    }
  };
  loadG(0, gp0); loadG(1, gp1); loadG(2, gp2); loadG(3, gp3);
  __syncthreads();

  auto step = [&](int t, f4* gv) {
    const int p0 = t & 1, p1 = p0 ^ 1;
    bf16x8 ah0 = *(const bf16x8*)&hb[p0][0][l15][q*8];
    bf16x8 ah1 = *(const bf16x8*)&hb[p0][0][l15][q*8 + 32];
    bf16x8 al0 = *(const bf16x8*)&hb[p0][1][l15][q*8];
    bf16x8 al1 = *(const bf16x8*)&hb[p0][1][l15][q*8 + 32];
    f4 a0 = gv[0], a1 = gv[1], a2 = gv[2], a3 = gv[3];
    a0 = mfma16(ah0, bh[0][0], a0); a0 = mfma16(ah1, bh[0][1], a0);
    a1 = mfma16(ah0, bh[1][0], a1); a1 = mfma16(ah1, bh[1][1], a1);
    a2 = mfma16(ah0, bh[2][0], a2); a2 = mfma16(ah1, bh[2][1], a2);
    a3 = mfma16(ah0, bh[3][0], a3); a3 = mfma16(ah1, bh[3][1], a3);
    a0 = mfma16(al0, bh[0][0], a0); a0 = mfma16(al1, bh[0][1], a0);
    a1 = mfma16(al0, bh[1][0], a1); a1 = mfma16(al1, bh[1][1], a1);
    a2 = mfma16(al0, bh[2][0], a2); a2 = mfma16(al1, bh[2][1], a2);
    a3 = mfma16(al0, bh[3][0], a3); a3 = mfma16(al1, bh[3][1], a3);
    a0 = mfma16(ah0, bl[0][0], a0); a0 = mfma16(ah1, bl[0][1], a0);
    a1 = mfma16(ah0, bl[1][0], a1); a1 = mfma16(ah1, bl[1][1], a1);
    a2 = mfma16(ah0, bl[2][0], a2); a2 = mfma16(ah1, bl[2][1], a2);
    a3 = mfma16(ah0, bl[3][0], a3); a3 = mfma16(ah1, bl[3][1], a3);
    if (lane < 16) {
      // in-lane: a0..a3 = gates i,f,g,o for hid col w*16+l15, batches 0-3
      f4 si = sigm4(a0);
      f4 sf = sigm4(a1);
      f4 tg = tanh4(a2);
      f4 so = sigm4(a3);
      ccv = sf*ccv + si*tg;
      f4 hv = so * tanh4(ccv);
      const int col = w*16 + l15;
      const int to = dir ? (SEQ-1 - t) : t;
      #pragma unroll
      for (int m = 0; m < 4; ++m) {
        float hh = (m==0) ? hv.x : (m==1) ? hv.y : (m==2) ? hv.z : hv.w;
        __bf16 hhi = (__bf16)hh;
        hb[p1][0][m][col] = hhi;
        hb[p1][1][m][col] = (__bf16)(hh - (float)hhi);
        out[((size_t)to*4 + m)*128 + dir*64 + col] = hh;
      }
    }
    barrier_lds_only();
  };

  for (int t0 = 0; t0 < SEQ; t0 += 4) {
    step(t0+0, gp0); if (t0+4 < SEQ) loadG(t0+4, gp0);
    step(t0+1, gp1); if (t0+5 < SEQ) loadG(t0+5, gp1);
    step(t0+2, gp2); if (t0+6 < SEQ) loadG(t0+6, gp2);
    step(t0+3, gp3); if (t0+7 < SEQ) loadG(t0+7, gp3);
  }
}

// final LayerNorm(concat) -> gate -> mix.  One wave per (t,b).
__global__ __launch_bounds__(256) void combine_k(
    const float* __restrict__ lstm, const float* __restrict__ mam,
    const float* __restrict__ lnw, const float* __restrict__ lnb,
    const float* __restrict__ gW, const float* __restrict__ gb,
    float* __restrict__ out)
{
  const int pair = blockIdx.x * 4 + (threadIdx.x >> 6);
  const int lane = threadIdx.x & 63;
  const float2 lv = *(const float2*)(lstm + (size_t)pair*128 + lane*2);
  const float2 mv = *(const float2*)(mam  + (size_t)pair*128 + lane*2);
  float s  = lv.x + lv.y + mv.x + mv.y;
  float sq = lv.x*lv.x + lv.y*lv.y + mv.x*mv.x + mv.y*mv.y;
  #pragma unroll
  for (int mm = 1; mm < 64; mm <<= 1) { s += __shfl_xor(s, mm, 64); sq += __shfl_xor(sq, mm, 64); }
  const float mean = s * (1.f/256.f);
  const float var  = sq * (1.f/256.f) - mean*mean;
  const float inv  = rsqrtf(var + 1e-5f);
  const int c0 = lane*2, c2 = 128 + lane*2;
  float n0 = (lv.x-mean)*inv*lnw[c0]   + lnb[c0];
  float n1 = (lv.y-mean)*inv*lnw[c0+1] + lnb[c0+1];
  float n2 = (mv.x-mean)*inv*lnw[c2]   + lnb[c2];
  float n3 = (mv.y-mean)*inv*lnw[c2+1] + lnb[c2+1];
  float dot = n0*gW[c0] + n1*gW[c0+1] + n2*gW[c2] + n3*gW[c2+1];
  #pragma unroll
  for (int mm = 1; mm < 64; mm <<= 1) dot += __shfl_xor(dot, mm, 64);
  const float gate = sigm(dot + gb[0]);
  float2 o;
  o.x = gate*lv.x + (1.f-gate)*mv.x;
  o.y = gate*lv.y + (1.f-gate)*mv.y;
  *(float2*)(out + (size_t)pair*128 + lane*2) = o;
}

extern "C" void kernel_launch(void* const* d_in, const int* in_sizes, int n_in,
                              void* d_out, int out_size, void* d_ws, size_t ws_size,
                              hipStream_t stream)
{
  const float* x       = (const float*)d_in[0];
  const float* Wih0    = (const float*)d_in[1];
  const float* WihR    = (const float*)d_in[2];
  const float* Whh     = (const float*)d_in[3];
  const float* bih     = (const float*)d_in[4];
  const float* bhh     = (const float*)d_in[5];
  const float* mprojW  = (const float*)d_in[6];
  const float* mprojB  = (const float*)d_in[7];
  const float* inprojW = (const float*)d_in[8];
  const float* convw   = (const float*)d_in[9];
  const float* convb   = (const float*)d_in[10];
  const float* xprojW  = (const float*)d_in[11];
  const float* dtW     = (const float*)d_in[12];
  const float* dtB     = (const float*)d_in[13];
  const float* Alog    = (const float*)d_in[14];
  const float* Dskip   = (const float*)d_in[15];
  const float* outprojW= (const float*)d_in[16];
  const float* lnw     = (const float*)d_in[17];
  const float* lnb     = (const float*)d_in[18];
  const float* gWt     = (const float*)d_in[19];
  const float* gb      = (const float*)d_in[20];

  float* WS = (float*)d_ws;
  const size_t M1 = 1048576;
  float* mamba_out = WS;            // [NM,128], persists to end
  float* P   = WS + M1;
  // mamba phase
  float* xm  = P;                   // [NM,128]
  float* xz  = P + M1;              // [NM,512]
  float* xc  = P + 5*M1;            // [NM,256]
  float* dbc = P + 7*M1;            // [NM,136]
  float* dtb = P + 7*M1 + 1310720;  // [NM,256]
  float* ysb = dtb + 2*M1;          // [NM,256]
  float* yc  = ysb + 2*M1;          // [NM,256]
  // lstm phase (mamba buffers except mamba_out are dead by then)
  float* G     = P;                 // [2][SEQ][256][4]
  float* lstmA = P + 4*M1;          // [NM,128]
  float* lstmB = P + 5*M1;          // [NM,128]
  float* outp  = (float*)d_out;

  dim3 blk(256);

  // ---- Mamba branch (all-parallel precompute + 1 sequential scan) ----
  gemm_k<<<dim3(2,128), blk, 0, stream>>>(x, 23, mprojW, nullptr, 128,
      mprojB, nullptr, nullptr, nullptr, xm, NM, 128, 23, 0);
  gemm_k<<<dim3(8,128), blk, 0, stream>>>(xm, 128, inprojW, nullptr, 512,
      nullptr, nullptr, nullptr, nullptr, xz, NM, 512, 128, 0);
  conv_silu_k<<<8192, blk, 0, stream>>>(xz, convw, convb, xc);
  gemm_k<<<dim3(3,128), blk, 0, stream>>>(xc, 256, xprojW, nullptr, 136,
      nullptr, nullptr, nullptr, nullptr, dbc, NM, 136, 256, 0);
  gemm_k<<<dim3(4,128), blk, 0, stream>>>(dbc, 136, dtW, nullptr, 256,
      dtB, nullptr, nullptr, nullptr, dtb, NM, 256, 8, 1);
  mamba_scan_k<<<256, blk, 0, stream>>>(dbc, dtb, xc, Alog, ysb);
  ycomb_k<<<8192, blk, 0, stream>>>(xz, ysb, xc, Dskip, yc);
  gemm_k<<<dim3(2,128), blk, 0, stream>>>(yc, 256, outprojW, nullptr, 128,
      nullptr, nullptr, nullptr, nullptr, mamba_out, NM, 128, 256, 0);

  // ---- LSTM: 4 layers, each = input-GEMM (parallel) + recurrent scan ----
  const float* lin = x;
  float* louts[4] = {lstmA, lstmB, lstmA, lstmB};
  for (int l = 0; l < 4; ++l) {
    const float* w0; const float* w1; int K;
    if (l == 0) { w0 = Wih0; w1 = Wih0 + 256*23; K = 23; }
    else {
      w0 = WihR + (size_t)((l-1)*2 + 0)*256*128;
      w1 = WihR + (size_t)((l-1)*2 + 1)*256*128;
      K = 128;
    }
    gemm_k<<<dim3(8,128), blk, 0, stream>>>(lin, K, w0, w1, 256,
        bih + (l*2+0)*256, bhh + (l*2+0)*256,
        bih + (l*2+1)*256, bhh + (l*2+1)*256,
        G, NM, 512, K, 2);
    lstm_scan_k<<<2, blk, 0, stream>>>(G, Whh + (size_t)l*2*256*64, louts[l]);
    lin = louts[l];
  }

  // ---- gate + mix ----
  combine_k<<<2048, blk, 0, stream>>>(lstmB, mamba_out, lnw, lnb, gWt, gb, outp);
}

// Round 6
// 6364.764 us; speedup vs baseline: 1.2246x; 1.2246x over previous
//
#include <hip/hip_runtime.h>

#define SEQ   2048
#define NM    8192        // SEQ*BATCH

typedef __attribute__((ext_vector_type(4))) float f4;
typedef __attribute__((ext_vector_type(8))) __bf16 bf16x8;

__device__ __forceinline__ float frcp(float x){ return __builtin_amdgcn_rcpf(x); }
__device__ __forceinline__ float sigm(float x){ return frcp(1.f + __expf(-x)); }
__device__ __forceinline__ float tanhf_(float x){ return 1.f - 2.f*frcp(__expf(2.f*x) + 1.f); }
__device__ __forceinline__ f4 mfma16(bf16x8 a, bf16x8 b, f4 c){
  return __builtin_amdgcn_mfma_f32_16x16x32_bf16(a, b, c, 0, 0, 0);
}
// LDS-only barrier: h-tile/glds coherence needs lgkmcnt(0) only; G prefetch
// global loads stay in flight across the barrier.
__device__ __forceinline__ void barrier_lds_only(){
  asm volatile("s_waitcnt lgkmcnt(0)\n\ts_barrier" ::: "memory");
}

// ---------------------------------------------------------------------------
// Generic tiled GEMM: out = A[M,K] @ W[N,K]^T (+bias), optional epilogues.
// mode 0: plain   mode 1: softplus   mode 2: LSTM-G store [dir][t][j][b], time-
// reversed for dir1.  W1 != null => rows >= Nhalf come from W1.
// ---------------------------------------------------------------------------
__global__ __launch_bounds__(256) void gemm_k(
    const float* __restrict__ A, int lda,
    const float* __restrict__ W0, const float* __restrict__ W1, int Nhalf,
    const float* __restrict__ b0a, const float* __restrict__ b0b,
    const float* __restrict__ b1a, const float* __restrict__ b1b,
    float* __restrict__ out, int M, int N, int K, int mode)
{
  __shared__ float As[64][17];
  __shared__ float Ws[64][17];
  const int tid = threadIdx.x;
  const int tn = tid & 15, tm = tid >> 4;
  const int n0 = blockIdx.x * 64, m0 = blockIdx.y * 64;
  const int srow = tid >> 2, sk = (tid & 3) * 4;
  float acc[4][4] = {};
  for (int k0 = 0; k0 < K; k0 += 16) {
    const int am = m0 + srow;
    #pragma unroll
    for (int q = 0; q < 4; ++q) {
      int k = k0 + sk + q;
      As[srow][sk + q] = (k < K) ? A[(size_t)am * lda + k] : 0.f;
    }
    const int wn = n0 + srow;
    const float* Wp = W0; int nn = wn;
    if (W1 != nullptr && wn >= Nhalf) { Wp = W1; nn = wn - Nhalf; }
    #pragma unroll
    for (int q = 0; q < 4; ++q) {
      int k = k0 + sk + q;
      Ws[srow][sk + q] = (wn < N && k < K) ? Wp[(size_t)nn * K + k] : 0.f;
    }
    __syncthreads();
    #pragma unroll
    for (int k = 0; k < 16; ++k) {
      float a[4], w[4];
      #pragma unroll
      for (int i = 0; i < 4; ++i) a[i] = As[tm*4+i][k];
      #pragma unroll
      for (int j = 0; j < 4; ++j) w[j] = Ws[tn*4+j][k];
      #pragma unroll
      for (int i = 0; i < 4; ++i)
        #pragma unroll
        for (int j = 0; j < 4; ++j) acc[i][j] += a[i]*w[j];
    }
    __syncthreads();
  }
  #pragma unroll
  for (int i = 0; i < 4; ++i) {
    #pragma unroll
    for (int j = 0; j < 4; ++j) {
      int m = m0 + tm*4 + i, n = n0 + tn*4 + j;
      if (n >= N) continue;
      float bias = 0.f;
      if (n < Nhalf) { if (b0a) bias += b0a[n]; if (b0b) bias += b0b[n]; }
      else { if (b1a) bias += b1a[n - Nhalf]; if (b1b) bias += b1b[n - Nhalf]; }
      float v = acc[i][j] + bias;
      if (mode == 1) { v = (v > 15.f) ? v : __logf(1.f + __expf(v)); }
      if (mode == 2) {
        int dd = n >> 8, jj = n & 255, t = m >> 2, b = m & 3;
        int tq = dd ? (SEQ - 1 - t) : t;
        out[((size_t)(dd*SEQ + tq) * 256 + jj) * 4 + b] = v;
      } else {
        out[(size_t)m * N + n] = v;
      }
    }
  }
}

// causal depthwise conv (4 taps) + SiLU.  xz: [NM,512] (xi = cols 0..255)
__global__ __launch_bounds__(256) void conv_silu_k(
    const float* __restrict__ xz, const float* __restrict__ cw,
    const float* __restrict__ cb, float* __restrict__ xc)
{
  int idx = blockIdx.x * 256 + threadIdx.x;
  int d = idx & 255, m = idx >> 8;
  int t = m >> 2, b = m & 3;
  float s = cb[d];
  #pragma unroll
  for (int k = 0; k < 4; ++k) {
    int tt = t - 3 + k;
    if (tt >= 0) s += xz[(size_t)(tt*4 + b) * 512 + d] * cw[d*4 + k];
  }
  xc[idx] = s * sigm(s);
}

// selective scan: wave per (b,d), lane per state s.
__global__ __launch_bounds__(256) void mamba_scan_k(
    const float* __restrict__ dbc, const float* __restrict__ dtb,
    const float* __restrict__ xc, const float* __restrict__ Alog,
    float* __restrict__ ys)
{
  const int wid = blockIdx.x * 4 + (threadIdx.x >> 6);
  const int lane = threadIdx.x & 63;
  const int b = wid >> 8, d = wid & 255;
  const float Av = -__expf(Alog[d*64 + lane]);
  const float* pB  = dbc + (size_t)b*136 + 8 + lane;
  const float* pC  = dbc + (size_t)b*136 + 72 + lane;
  const float* pdt = dtb + (size_t)b*256 + d;
  const float* px  = xc  + (size_t)b*256 + d;
  float* py = ys + (size_t)b*256 + d;
  float h = 0.f;
  float Bv = pB[0], Cv = pC[0], dtv = pdt[0], xv = px[0];
  #pragma unroll 2
  for (int t = 0; t < SEQ; ++t) {
    float Bn = 0.f, Cn = 0.f, dtn = 0.f, xn = 0.f;
    if (t + 1 < SEQ) {
      size_t od = (size_t)(t+1) * 544;   // 4 rows * 136
      size_t ox = (size_t)(t+1) * 1024;  // 4 rows * 256
      Bn = pB[od]; Cn = pC[od]; dtn = pdt[ox]; xn = px[ox];
    }
    float a = __expf(dtv * Av);
    h = a*h + (dtv*xv)*Bv;
    float p = h * Cv;
    #pragma unroll
    for (int mm = 1; mm < 64; mm <<= 1) p += __shfl_xor(p, mm, 64);
    if (lane == 0) py[(size_t)t * 1024] = p;
    Bv = Bn; Cv = Cn; dtv = dtn; xv = xn;
  }
}

// y = (ys + xc*D) * silu(z)
__global__ __launch_bounds__(256) void ycomb_k(
    const float* __restrict__ xz, const float* __restrict__ ys,
    const float* __restrict__ xc, const float* __restrict__ Dsk,
    float* __restrict__ yc)
{
  int idx = blockIdx.x * 256 + threadIdx.x;
  int d = idx & 255, m = idx >> 8;
  float z = xz[(size_t)m * 512 + 256 + d];
  yc[idx] = (ys[idx] + xc[idx]*Dsk[d]) * z * sigm(z);
}

// ---------------------------------------------------------------------------
// LSTM recurrent scan: one block per direction, 512 threads = 8 waves
// (2 waves per SIMD -> co-scheduling, the single change vs R2's 4-wave form).
// MFMA phase: wave w owns gate-tiles {w, w+8} (12 MFMAs as 2x6-deep chains,
// R2 ordering); all 8 waves write C-frags to glds[tile][col][batch]; lgkm
// barrier.  Activation phase: waves 0-3 run R2's exact path (1 value/lane,
// glds reads for i/f/g/o = tiles w, w+4, w+8, w+12), write h hi/lo to hb and
// out; waves 4-7 idle at the second lgkm barrier.  Per-SIMD: MFMA pipe time
// unchanged (24 MFMAs = 384 cyc) but the two co-resident waves hide each
// other's ds_read/chain-tail/glds latencies; act phase has exactly one
// active wave per SIMD (R5 lesson: never concentrate transcendentals).
// ---------------------------------------------------------------------------
#define HROW 80   // padded row stride (bf16)
__global__ __launch_bounds__(512, 1) void lstm_scan_k(
    const float* __restrict__ G,    // [2][SEQ][256][4]
    const float* __restrict__ Whh,  // [2][256][64] (layer base)
    float* __restrict__ out)        // [SEQ][4][128]
{
  const int dir = blockIdx.x;
  const int tid = threadIdx.x;
  const int w = tid >> 6, lane = tid & 63;   // w in 0..7
  const int l15 = lane & 15, q = lane >> 4;

  __shared__ __bf16 hb[2][2][16][HROW];   // [buf][hi/lo][m=batch][k=n]
  __shared__ float glds[16][16][4];       // [gate-tile][col][batch]

  for (int i = tid; i < 2*2*16*HROW; i += 512) ((__bf16*)hb)[i] = (__bf16)0.f;

  const float* Gd = G + (size_t)dir * SEQ * 1024;
  const float* Wd = Whh + dir * 256 * 64;

  const int T0 = w, T1 = w + 8;   // this wave's gate tiles (rows T*16..T*16+15)

  // B fragments (constant over t), hi/lo split of W
  bf16x8 bh[2][2], bl[2][2];
  #pragma unroll
  for (int s = 0; s < 2; ++s) {
    const int j = ((s == 0) ? T0 : T1)*16 + l15;
    #pragma unroll
    for (int kt = 0; kt < 2; ++kt) {
      const float* src = Wd + j*64 + kt*32 + q*8;
      #pragma unroll
      for (int e = 0; e < 8; ++e) {
        float v = src[e];
        __bf16 hi = (__bf16)v;
        bh[s][kt][e] = hi;
        bl[s][kt][e] = (__bf16)(v - (float)hi);
      }
    }
  }

  float cc = 0.f;                      // cell state (waves 0-3 only)
  f4 gp0[2], gp1[2], gp2[2], gp3[2];

  auto loadG = [&](int t, f4* gv) {
    gv[0] = *(const f4*)(Gd + ((size_t)t*256 + T0*16 + l15)*4);
    gv[1] = *(const f4*)(Gd + ((size_t)t*256 + T1*16 + l15)*4);
  };
  loadG(0, gp0); loadG(1, gp1); loadG(2, gp2); loadG(3, gp3);
  __syncthreads();

  auto step = [&](int t, f4* gv) {
    const int p0 = t & 1, p1 = p0 ^ 1;
    bf16x8 ah0 = *(const bf16x8*)&hb[p0][0][l15][q*8];
    bf16x8 ah1 = *(const bf16x8*)&hb[p0][0][l15][q*8 + 32];
    bf16x8 al0 = *(const bf16x8*)&hb[p0][1][l15][q*8];
    bf16x8 al1 = *(const bf16x8*)&hb[p0][1][l15][q*8 + 32];
    f4 a0 = gv[0], a1 = gv[1];
    a0 = mfma16(ah0, bh[0][0], a0); a0 = mfma16(ah1, bh[0][1], a0);
    a1 = mfma16(ah0, bh[1][0], a1); a1 = mfma16(ah1, bh[1][1], a1);
    a0 = mfma16(al0, bh[0][0], a0); a0 = mfma16(al1, bh[0][1], a0);
    a1 = mfma16(al0, bh[1][0], a1); a1 = mfma16(al1, bh[1][1], a1);
    a0 = mfma16(ah0, bl[0][0], a0); a0 = mfma16(ah1, bl[0][1], a0);
    a1 = mfma16(ah0, bl[1][0], a1); a1 = mfma16(ah1, bl[1][1], a1);
    if (lane < 16) {
      *(f4*)&glds[T0][l15][0] = a0;
      *(f4*)&glds[T1][l15][0] = a1;
    }
    barrier_lds_only();               // gates visible to act waves
    if (w < 4) {
      float gi = glds[w     ][l15][q];
      float gf = glds[w +  4][l15][q];
      float gt = glds[w +  8][l15][q];
      float go = glds[w + 12][l15][q];
      cc = sigm(gf)*cc + sigm(gi)*tanhf_(gt);
      float hh = sigm(go)*tanhf_(cc);
      __bf16 hhi = (__bf16)hh;
      hb[p1][0][q][w*16 + l15] = hhi;
      hb[p1][1][q][w*16 + l15] = (__bf16)(hh - (float)hhi);
      const int to = dir ? (SEQ-1 - t) : t;
      out[((size_t)to*4 + q)*128 + dir*64 + w*16 + l15] = hh;
    }
    barrier_lds_only();               // h visible to all waves
  };

  for (int t0 = 0; t0 < SEQ; t0 += 4) {
    step(t0+0, gp0); if (t0+4 < SEQ) loadG(t0+4, gp0);
    step(t0+1, gp1); if (t0+5 < SEQ) loadG(t0+5, gp1);
    step(t0+2, gp2); if (t0+6 < SEQ) loadG(t0+6, gp2);
    step(t0+3, gp3); if (t0+7 < SEQ) loadG(t0+7, gp3);
  }
}

// final LayerNorm(concat) -> gate -> mix.  One wave per (t,b).
__global__ __launch_bounds__(256) void combine_k(
    const float* __restrict__ lstm, const float* __restrict__ mam,
    const float* __restrict__ lnw, const float* __restrict__ lnb,
    const float* __restrict__ gW, const float* __restrict__ gb,
    float* __restrict__ out)
{
  const int pair = blockIdx.x * 4 + (threadIdx.x >> 6);
  const int lane = threadIdx.x & 63;
  const float2 lv = *(const float2*)(lstm + (size_t)pair*128 + lane*2);
  const float2 mv = *(const float2*)(mam  + (size_t)pair*128 + lane*2);
  float s  = lv.x + lv.y + mv.x + mv.y;
  float sq = lv.x*lv.x + lv.y*lv.y + mv.x*mv.x + mv.y*mv.y;
  #pragma unroll
  for (int mm = 1; mm < 64; mm <<= 1) { s += __shfl_xor(s, mm, 64); sq += __shfl_xor(sq, mm, 64); }
  const float mean = s * (1.f/256.f);
  const float var  = sq * (1.f/256.f) - mean*mean;
  const float inv  = rsqrtf(var + 1e-5f);
  const int c0 = lane*2, c2 = 128 + lane*2;
  float n0 = (lv.x-mean)*inv*lnw[c0]   + lnb[c0];
  float n1 = (lv.y-mean)*inv*lnw[c0+1] + lnb[c0+1];
  float n2 = (mv.x-mean)*inv*lnw[c2]   + lnb[c2];
  float n3 = (mv.y-mean)*inv*lnw[c2+1] + lnb[c2+1];
  float dot = n0*gW[c0] + n1*gW[c0+1] + n2*gW[c2] + n3*gW[c2+1];
  #pragma unroll
  for (int mm = 1; mm < 64; mm <<= 1) dot += __shfl_xor(dot, mm, 64);
  const float gate = sigm(dot + gb[0]);
  float2 o;
  o.x = gate*lv.x + (1.f-gate)*mv.x;
  o.y = gate*lv.y + (1.f-gate)*mv.y;
  *(float2*)(out + (size_t)pair*128 + lane*2) = o;
}

extern "C" void kernel_launch(void* const* d_in, const int* in_sizes, int n_in,
                              void* d_out, int out_size, void* d_ws, size_t ws_size,
                              hipStream_t stream)
{
  const float* x       = (const float*)d_in[0];
  const float* Wih0    = (const float*)d_in[1];
  const float* WihR    = (const float*)d_in[2];
  const float* Whh     = (const float*)d_in[3];
  const float* bih     = (const float*)d_in[4];
  const float* bhh     = (const float*)d_in[5];
  const float* mprojW  = (const float*)d_in[6];
  const float* mprojB  = (const float*)d_in[7];
  const float* inprojW = (const float*)d_in[8];
  const float* convw   = (const float*)d_in[9];
  const float* convb   = (const float*)d_in[10];
  const float* xprojW  = (const float*)d_in[11];
  const float* dtW     = (const float*)d_in[12];
  const float* dtB     = (const float*)d_in[13];
  const float* Alog    = (const float*)d_in[14];
  const float* Dskip   = (const float*)d_in[15];
  const float* outprojW= (const float*)d_in[16];
  const float* lnw     = (const float*)d_in[17];
  const float* lnb     = (const float*)d_in[18];
  const float* gWt     = (const float*)d_in[19];
  const float* gb      = (const float*)d_in[20];

  float* WS = (float*)d_ws;
  const size_t M1 = 1048576;
  float* mamba_out = WS;            // [NM,128], persists to end
  float* P   = WS + M1;
  // mamba phase
  float* xm  = P;                   // [NM,128]
  float* xz  = P + M1;              // [NM,512]
  float* xc  = P + 5*M1;            // [NM,256]
  float* dbc = P + 7*M1;            // [NM,136]
  float* dtb = P + 7*M1 + 1310720;  // [NM,256]
  float* ysb = dtb + 2*M1;          // [NM,256]
  float* yc  = ysb + 2*M1;          // [NM,256]
  // lstm phase (mamba buffers except mamba_out are dead by then)
  float* G     = P;                 // [2][SEQ][256][4]
  float* lstmA = P + 4*M1;          // [NM,128]
  float* lstmB = P + 5*M1;          // [NM,128]
  float* outp  = (float*)d_out;

  dim3 blk(256);

  // ---- Mamba branch (all-parallel precompute + 1 sequential scan) ----
  gemm_k<<<dim3(2,128), blk, 0, stream>>>(x, 23, mprojW, nullptr, 128,
      mprojB, nullptr, nullptr, nullptr, xm, NM, 128, 23, 0);
  gemm_k<<<dim3(8,128), blk, 0, stream>>>(xm, 128, inprojW, nullptr, 512,
      nullptr, nullptr, nullptr, nullptr, xz, NM, 512, 128, 0);
  conv_silu_k<<<8192, blk, 0, stream>>>(xz, convw, convb, xc);
  gemm_k<<<dim3(3,128), blk, 0, stream>>>(xc, 256, xprojW, nullptr, 136,
      nullptr, nullptr, nullptr, nullptr, dbc, NM, 136, 256, 0);
  gemm_k<<<dim3(4,128), blk, 0, stream>>>(dbc, 136, dtW, nullptr, 256,
      dtB, nullptr, nullptr, nullptr, dtb, NM, 256, 8, 1);
  mamba_scan_k<<<256, blk, 0, stream>>>(dbc, dtb, xc, Alog, ysb);
  ycomb_k<<<8192, blk, 0, stream>>>(xz, ysb, xc, Dskip, yc);
  gemm_k<<<dim3(2,128), blk, 0, stream>>>(yc, 256, outprojW, nullptr, 128,
      nullptr, nullptr, nullptr, nullptr, mamba_out, NM, 128, 256, 0);

  // ---- LSTM: 4 layers, each = input-GEMM (parallel) + recurrent scan ----
  const float* lin = x;
  float* louts[4] = {lstmA, lstmB, lstmA, lstmB};
  for (int l = 0; l < 4; ++l) {
    const float* w0; const float* w1; int K;
    if (l == 0) { w0 = Wih0; w1 = Wih0 + 256*23; K = 23; }
    else {
      w0 = WihR + (size_t)((l-1)*2 + 0)*256*128;
      w1 = WihR + (size_t)((l-1)*2 + 1)*256*128;
      K = 128;
    }
    gemm_k<<<dim3(8,128), blk, 0, stream>>>(lin, K, w0, w1, 256,
        bih + (l*2+0)*256, bhh + (l*2+0)*256,
        bih + (l*2+1)*256, bhh + (l*2+1)*256,
        G, NM, 512, K, 2);
    lstm_scan_k<<<2, dim3(512), 0, stream>>>(G, Whh + (size_t)l*2*256*64, louts[l]);
    lin = louts[l];
  }

  // ---- gate + mix ----
  combine_k<<<2048, blk, 0, stream>>>(lstmB, mamba_out, lnw, lnb, gWt, gb, outp);
}

// Round 7
// 5513.715 us; speedup vs baseline: 1.4136x; 1.1544x over previous
//
#include <hip/hip_runtime.h>

#define SEQ   2048
#define NM    8192        // SEQ*BATCH

typedef __attribute__((ext_vector_type(4))) float f4;
typedef _Float16 f16x8 __attribute__((ext_vector_type(8)));

__device__ __forceinline__ float frcp(float x){ return __builtin_amdgcn_rcpf(x); }
__device__ __forceinline__ float sigm(float x){ return frcp(1.f + __expf(-x)); }
__device__ __forceinline__ float tanhf_(float x){ return 1.f - 2.f*frcp(__expf(2.f*x) + 1.f); }
__device__ __forceinline__ f4 mfma16h(f16x8 a, f16x8 b, f4 c){
  return __builtin_amdgcn_mfma_f32_16x16x32_f16(a, b, c, 0, 0, 0);
}
// LDS-only barrier: h-tile/glds coherence needs lgkmcnt(0) only; G prefetch
// global loads stay in flight across the barrier.
__device__ __forceinline__ void barrier_lds_only(){
  asm volatile("s_waitcnt lgkmcnt(0)\n\ts_barrier" ::: "memory");
}

// ---------------------------------------------------------------------------
// Generic tiled GEMM: out = A[M,K] @ W[N,K]^T (+bias), optional epilogues.
// mode 0: plain   mode 1: softplus   mode 2: LSTM-G store [dir][t][j][b], time-
// reversed for dir1.  W1 != null => rows >= Nhalf come from W1.
// ---------------------------------------------------------------------------
__global__ __launch_bounds__(256) void gemm_k(
    const float* __restrict__ A, int lda,
    const float* __restrict__ W0, const float* __restrict__ W1, int Nhalf,
    const float* __restrict__ b0a, const float* __restrict__ b0b,
    const float* __restrict__ b1a, const float* __restrict__ b1b,
    float* __restrict__ out, int M, int N, int K, int mode)
{
  __shared__ float As[64][17];
  __shared__ float Ws[64][17];
  const int tid = threadIdx.x;
  const int tn = tid & 15, tm = tid >> 4;
  const int n0 = blockIdx.x * 64, m0 = blockIdx.y * 64;
  const int srow = tid >> 2, sk = (tid & 3) * 4;
  float acc[4][4] = {};
  for (int k0 = 0; k0 < K; k0 += 16) {
    const int am = m0 + srow;
    #pragma unroll
    for (int q = 0; q < 4; ++q) {
      int k = k0 + sk + q;
      As[srow][sk + q] = (k < K) ? A[(size_t)am * lda + k] : 0.f;
    }
    const int wn = n0 + srow;
    const float* Wp = W0; int nn = wn;
    if (W1 != nullptr && wn >= Nhalf) { Wp = W1; nn = wn - Nhalf; }
    #pragma unroll
    for (int q = 0; q < 4; ++q) {
      int k = k0 + sk + q;
      Ws[srow][sk + q] = (wn < N && k < K) ? Wp[(size_t)nn * K + k] : 0.f;
    }
    __syncthreads();
    #pragma unroll
    for (int k = 0; k < 16; ++k) {
      float a[4], w[4];
      #pragma unroll
      for (int i = 0; i < 4; ++i) a[i] = As[tm*4+i][k];
      #pragma unroll
      for (int j = 0; j < 4; ++j) w[j] = Ws[tn*4+j][k];
      #pragma unroll
      for (int i = 0; i < 4; ++i)
        #pragma unroll
        for (int j = 0; j < 4; ++j) acc[i][j] += a[i]*w[j];
    }
    __syncthreads();
  }
  #pragma unroll
  for (int i = 0; i < 4; ++i) {
    #pragma unroll
    for (int j = 0; j < 4; ++j) {
      int m = m0 + tm*4 + i, n = n0 + tn*4 + j;
      if (n >= N) continue;
      float bias = 0.f;
      if (n < Nhalf) { if (b0a) bias += b0a[n]; if (b0b) bias += b0b[n]; }
      else { if (b1a) bias += b1a[n - Nhalf]; if (b1b) bias += b1b[n - Nhalf]; }
      float v = acc[i][j] + bias;
      if (mode == 1) { v = (v > 15.f) ? v : __logf(1.f + __expf(v)); }
      if (mode == 2) {
        int dd = n >> 8, jj = n & 255, t = m >> 2, b = m & 3;
        int tq = dd ? (SEQ - 1 - t) : t;
        out[((size_t)(dd*SEQ + tq) * 256 + jj) * 4 + b] = v;
      } else {
        out[(size_t)m * N + n] = v;
      }
    }
  }
}

// causal depthwise conv (4 taps) + SiLU.  xz: [NM,512] (xi = cols 0..255)
__global__ __launch_bounds__(256) void conv_silu_k(
    const float* __restrict__ xz, const float* __restrict__ cw,
    const float* __restrict__ cb, float* __restrict__ xc)
{
  int idx = blockIdx.x * 256 + threadIdx.x;
  int d = idx & 255, m = idx >> 8;
  int t = m >> 2, b = m & 3;
  float s = cb[d];
  #pragma unroll
  for (int k = 0; k < 4; ++k) {
    int tt = t - 3 + k;
    if (tt >= 0) s += xz[(size_t)(tt*4 + b) * 512 + d] * cw[d*4 + k];
  }
  xc[idx] = s * sigm(s);
}

// selective scan: wave per (b,d), lane per state s.
__global__ __launch_bounds__(256) void mamba_scan_k(
    const float* __restrict__ dbc, const float* __restrict__ dtb,
    const float* __restrict__ xc, const float* __restrict__ Alog,
    float* __restrict__ ys)
{
  const int wid = blockIdx.x * 4 + (threadIdx.x >> 6);
  const int lane = threadIdx.x & 63;
  const int b = wid >> 8, d = wid & 255;
  const float Av = -__expf(Alog[d*64 + lane]);
  const float* pB  = dbc + (size_t)b*136 + 8 + lane;
  const float* pC  = dbc + (size_t)b*136 + 72 + lane;
  const float* pdt = dtb + (size_t)b*256 + d;
  const float* px  = xc  + (size_t)b*256 + d;
  float* py = ys + (size_t)b*256 + d;
  float h = 0.f;
  float Bv = pB[0], Cv = pC[0], dtv = pdt[0], xv = px[0];
  #pragma unroll 2
  for (int t = 0; t < SEQ; ++t) {
    float Bn = 0.f, Cn = 0.f, dtn = 0.f, xn = 0.f;
    if (t + 1 < SEQ) {
      size_t od = (size_t)(t+1) * 544;   // 4 rows * 136
      size_t ox = (size_t)(t+1) * 1024;  // 4 rows * 256
      Bn = pB[od]; Cn = pC[od]; dtn = pdt[ox]; xn = px[ox];
    }
    float a = __expf(dtv * Av);
    h = a*h + (dtv*xv)*Bv;
    float p = h * Cv;
    #pragma unroll
    for (int mm = 1; mm < 64; mm <<= 1) p += __shfl_xor(p, mm, 64);
    if (lane == 0) py[(size_t)t * 1024] = p;
    Bv = Bn; Cv = Cn; dtv = dtn; xv = xn;
  }
}

// y = (ys + xc*D) * silu(z)
__global__ __launch_bounds__(256) void ycomb_k(
    const float* __restrict__ xz, const float* __restrict__ ys,
    const float* __restrict__ xc, const float* __restrict__ Dsk,
    float* __restrict__ yc)
{
  int idx = blockIdx.x * 256 + threadIdx.x;
  int d = idx & 255, m = idx >> 8;
  float z = xz[(size_t)m * 512 + 256 + d];
  yc[idx] = (ys[idx] + xc[idx]*Dsk[d]) * z * sigm(z);
}

// ---------------------------------------------------------------------------
// LSTM recurrent scan: one block per direction, 512 threads = 8 waves,
// split-phase (R6 structure).  THIS ROUND'S single change: the 3-pass bf16
// hi/lo precision scheme is replaced by SINGLE-PASS F16 MFMA
// (mfma_f32_16x16x32_f16).  f16's 11-bit mantissa on W (~0.04) and h (~0.3)
// gives per-gate dot error ~3e-5/step — comparable to the 3-pass bf16
// residual — while cutting the MFMA pipe from 24 to 8 MFMAs/step/SIMD-pair
// (384 -> 128 cyc), chains 6->2 deep, a-frag ds_reads 4->2, h store 2->1
// plane.  G seed, c, h, and the output stay fp32.
// MFMA phase: wave w owns gate-tiles {w, w+8} (4 MFMAs, 2x2-deep); C-frags
// to glds; lgkm barrier.  Act phase: waves 0-3, R2's exact path (1 val/lane).
// ---------------------------------------------------------------------------
#define HROW 80   // padded row stride (f16)
__global__ __launch_bounds__(512, 1) void lstm_scan_k(
    const float* __restrict__ G,    // [2][SEQ][256][4]
    const float* __restrict__ Whh,  // [2][256][64] (layer base)
    float* __restrict__ out)        // [SEQ][4][128]
{
  const int dir = blockIdx.x;
  const int tid = threadIdx.x;
  const int w = tid >> 6, lane = tid & 63;   // w in 0..7
  const int l15 = lane & 15, q = lane >> 4;

  __shared__ _Float16 hb[2][16][HROW];    // [buf][m=batch][k=n]
  __shared__ float glds[16][16][4];       // [gate-tile][col][batch]

  for (int i = tid; i < 2*16*HROW; i += 512) ((_Float16*)hb)[i] = (_Float16)0.f;

  const float* Gd = G + (size_t)dir * SEQ * 1024;
  const float* Wd = Whh + dir * 256 * 64;

  const int T0 = w, T1 = w + 8;   // this wave's gate tiles (rows T*16..T*16+15)

  // B fragments (constant over t), f16
  f16x8 bh[2][2];
  #pragma unroll
  for (int s = 0; s < 2; ++s) {
    const int j = ((s == 0) ? T0 : T1)*16 + l15;
    #pragma unroll
    for (int kt = 0; kt < 2; ++kt) {
      const float* src = Wd + j*64 + kt*32 + q*8;
      #pragma unroll
      for (int e = 0; e < 8; ++e) bh[s][kt][e] = (_Float16)src[e];
    }
  }

  float cc = 0.f;                      // cell state (waves 0-3 only)
  f4 gp0[2], gp1[2], gp2[2], gp3[2];

  auto loadG = [&](int t, f4* gv) {
    gv[0] = *(const f4*)(Gd + ((size_t)t*256 + T0*16 + l15)*4);
    gv[1] = *(const f4*)(Gd + ((size_t)t*256 + T1*16 + l15)*4);
  };
  loadG(0, gp0); loadG(1, gp1); loadG(2, gp2); loadG(3, gp3);
  __syncthreads();

  auto step = [&](int t, f4* gv) {
    const int p0 = t & 1, p1 = p0 ^ 1;
    f16x8 ah0 = *(const f16x8*)&hb[p0][l15][q*8];
    f16x8 ah1 = *(const f16x8*)&hb[p0][l15][q*8 + 32];
    f4 a0 = gv[0], a1 = gv[1];
    a0 = mfma16h(ah0, bh[0][0], a0); a0 = mfma16h(ah1, bh[0][1], a0);
    a1 = mfma16h(ah0, bh[1][0], a1); a1 = mfma16h(ah1, bh[1][1], a1);
    if (lane < 16) {
      *(f4*)&glds[T0][l15][0] = a0;
      *(f4*)&glds[T1][l15][0] = a1;
    }
    barrier_lds_only();               // gates visible to act waves
    if (w < 4) {
      float gi = glds[w     ][l15][q];
      float gf = glds[w +  4][l15][q];
      float gt = glds[w +  8][l15][q];
      float go = glds[w + 12][l15][q];
      cc = sigm(gf)*cc + sigm(gi)*tanhf_(gt);
      float hh = sigm(go)*tanhf_(cc);
      hb[p1][q][w*16 + l15] = (_Float16)hh;
      const int to = dir ? (SEQ-1 - t) : t;
      out[((size_t)to*4 + q)*128 + dir*64 + w*16 + l15] = hh;
    }
    barrier_lds_only();               // h visible to all waves
  };

  for (int t0 = 0; t0 < SEQ; t0 += 4) {
    step(t0+0, gp0); if (t0+4 < SEQ) loadG(t0+4, gp0);
    step(t0+1, gp1); if (t0+5 < SEQ) loadG(t0+5, gp1);
    step(t0+2, gp2); if (t0+6 < SEQ) loadG(t0+6, gp2);
    step(t0+3, gp3); if (t0+7 < SEQ) loadG(t0+7, gp3);
  }
}

// final LayerNorm(concat) -> gate -> mix.  One wave per (t,b).
__global__ __launch_bounds__(256) void combine_k(
    const float* __restrict__ lstm, const float* __restrict__ mam,
    const float* __restrict__ lnw, const float* __restrict__ lnb,
    const float* __restrict__ gW, const float* __restrict__ gb,
    float* __restrict__ out)
{
  const int pair = blockIdx.x * 4 + (threadIdx.x >> 6);
  const int lane = threadIdx.x & 63;
  const float2 lv = *(const float2*)(lstm + (size_t)pair*128 + lane*2);
  const float2 mv = *(const float2*)(mam  + (size_t)pair*128 + lane*2);
  float s  = lv.x + lv.y + mv.x + mv.y;
  float sq = lv.x*lv.x + lv.y*lv.y + mv.x*mv.x + mv.y*mv.y;
  #pragma unroll
  for (int mm = 1; mm < 64; mm <<= 1) { s += __shfl_xor(s, mm, 64); sq += __shfl_xor(sq, mm, 64); }
  const float mean = s * (1.f/256.f);
  const float var  = sq * (1.f/256.f) - mean*mean;
  const float inv  = rsqrtf(var + 1e-5f);
  const int c0 = lane*2, c2 = 128 + lane*2;
  float n0 = (lv.x-mean)*inv*lnw[c0]   + lnb[c0];
  float n1 = (lv.y-mean)*inv*lnw[c0+1] + lnb[c0+1];
  float n2 = (mv.x-mean)*inv*lnw[c2]   + lnb[c2];
  float n3 = (mv.y-mean)*inv*lnw[c2+1] + lnb[c2+1];
  float dot = n0*gW[c0] + n1*gW[c0+1] + n2*gW[c2] + n3*gW[c2+1];
  #pragma unroll
  for (int mm = 1; mm < 64; mm <<= 1) dot += __shfl_xor(dot, mm, 64);
  const float gate = sigm(dot + gb[0]);
  float2 o;
  o.x = gate*lv.x + (1.f-gate)*mv.x;
  o.y = gate*lv.y + (1.f-gate)*mv.y;
  *(float2*)(out + (size_t)pair*128 + lane*2) = o;
}

extern "C" void kernel_launch(void* const* d_in, const int* in_sizes, int n_in,
                              void* d_out, int out_size, void* d_ws, size_t ws_size,
                              hipStream_t stream)
{
  const float* x       = (const float*)d_in[0];
  const float* Wih0    = (const float*)d_in[1];
  const float* WihR    = (const float*)d_in[2];
  const float* Whh     = (const float*)d_in[3];
  const float* bih     = (const float*)d_in[4];
  const float* bhh     = (const float*)d_in[5];
  const float* mprojW  = (const float*)d_in[6];
  const float* mprojB  = (const float*)d_in[7];
  const float* inprojW = (const float*)d_in[8];
  const float* convw   = (const float*)d_in[9];
  const float* convb   = (const float*)d_in[10];
  const float* xprojW  = (const float*)d_in[11];
  const float* dtW     = (const float*)d_in[12];
  const float* dtB     = (const float*)d_in[13];
  const float* Alog    = (const float*)d_in[14];
  const float* Dskip   = (const float*)d_in[15];
  const float* outprojW= (const float*)d_in[16];
  const float* lnw     = (const float*)d_in[17];
  const float* lnb     = (const float*)d_in[18];
  const float* gWt     = (const float*)d_in[19];
  const float* gb      = (const float*)d_in[20];

  float* WS = (float*)d_ws;
  const size_t M1 = 1048576;
  float* mamba_out = WS;            // [NM,128], persists to end
  float* P   = WS + M1;
  // mamba phase
  float* xm  = P;                   // [NM,128]
  float* xz  = P + M1;              // [NM,512]
  float* xc  = P + 5*M1;            // [NM,256]
  float* dbc = P + 7*M1;            // [NM,136]
  float* dtb = P + 7*M1 + 1310720;  // [NM,256]
  float* ysb = dtb + 2*M1;          // [NM,256]
  float* yc  = ysb + 2*M1;          // [NM,256]
  // lstm phase (mamba buffers except mamba_out are dead by then)
  float* G     = P;                 // [2][SEQ][256][4]
  float* lstmA = P + 4*M1;          // [NM,128]
  float* lstmB = P + 5*M1;          // [NM,128]
  float* outp  = (float*)d_out;

  dim3 blk(256);

  // ---- Mamba branch (all-parallel precompute + 1 sequential scan) ----
  gemm_k<<<dim3(2,128), blk, 0, stream>>>(x, 23, mprojW, nullptr, 128,
      mprojB, nullptr, nullptr, nullptr, xm, NM, 128, 23, 0);
  gemm_k<<<dim3(8,128), blk, 0, stream>>>(xm, 128, inprojW, nullptr, 512,
      nullptr, nullptr, nullptr, nullptr, xz, NM, 512, 128, 0);
  conv_silu_k<<<8192, blk, 0, stream>>>(xz, convw, convb, xc);
  gemm_k<<<dim3(3,128), blk, 0, stream>>>(xc, 256, xprojW, nullptr, 136,
      nullptr, nullptr, nullptr, nullptr, dbc, NM, 136, 256, 0);
  gemm_k<<<dim3(4,128), blk, 0, stream>>>(dbc, 136, dtW, nullptr, 256,
      dtB, nullptr, nullptr, nullptr, dtb, NM, 256, 8, 1);
  mamba_scan_k<<<256, blk, 0, stream>>>(dbc, dtb, xc, Alog, ysb);
  ycomb_k<<<8192, blk, 0, stream>>>(xz, ysb, xc, Dskip, yc);
  gemm_k<<<dim3(2,128), blk, 0, stream>>>(yc, 256, outprojW, nullptr, 128,
      nullptr, nullptr, nullptr, nullptr, mamba_out, NM, 128, 256, 0);

  // ---- LSTM: 4 layers, each = input-GEMM (parallel) + recurrent scan ----
  const float* lin = x;
  float* louts[4] = {lstmA, lstmB, lstmA, lstmB};
  for (int l = 0; l < 4; ++l) {
    const float* w0; const float* w1; int K;
    if (l == 0) { w0 = Wih0; w1 = Wih0 + 256*23; K = 23; }
    else {
      w0 = WihR + (size_t)((l-1)*2 + 0)*256*128;
      w1 = WihR + (size_t)((l-1)*2 + 1)*256*128;
      K = 128;
    }
    gemm_k<<<dim3(8,128), blk, 0, stream>>>(lin, K, w0, w1, 256,
        bih + (l*2+0)*256, bhh + (l*2+0)*256,
        bih + (l*2+1)*256, bhh + (l*2+1)*256,
        G, NM, 512, K, 2);
    lstm_scan_k<<<2, dim3(512), 0, stream>>>(G, Whh + (size_t)l*2*256*64, louts[l]);
    lin = louts[l];
  }

  // ---- gate + mix ----
  combine_k<<<2048, blk, 0, stream>>>(lstmB, mamba_out, lnw, lnb, gWt, gb, outp);
}

// Round 8
// 4655.579 us; speedup vs baseline: 1.6742x; 1.1843x over previous
//
#include <hip/hip_runtime.h>

#define SEQ   2048
#define NM    8192        // SEQ*BATCH

typedef __attribute__((ext_vector_type(4))) float f4;
typedef _Float16 f16x8 __attribute__((ext_vector_type(8)));

__device__ __forceinline__ float frcp(float x){ return __builtin_amdgcn_rcpf(x); }
__device__ __forceinline__ float sigm(float x){ return frcp(1.f + __expf(-x)); }
__device__ __forceinline__ float tanhf_(float x){ return 1.f - 2.f*frcp(__expf(2.f*x) + 1.f); }
__device__ __forceinline__ f4 mfma16h(f16x8 a, f16x8 b, f4 c){
  return __builtin_amdgcn_mfma_f32_16x16x32_f16(a, b, c, 0, 0, 0);
}
// LDS-only barrier: scan h/glds coherence needs lgkmcnt(0) only; G prefetch
// global loads stay in flight across the barrier.
__device__ __forceinline__ void barrier_lds_only(){
  asm volatile("s_waitcnt lgkmcnt(0)\n\ts_barrier" ::: "memory");
}

// ---------------------------------------------------------------------------
// Generic tiled GEMM (256 thr): out = A[M,K] @ W[N,K]^T (+bias), epilogues.
// mode 0: plain   mode 2: LSTM-G store [dir][t][j][b], time-reversed for dir1.
// ---------------------------------------------------------------------------
__global__ __launch_bounds__(256) void gemm_k(
    const float* __restrict__ A, int lda,
    const float* __restrict__ W0, const float* __restrict__ W1, int Nhalf,
    const float* __restrict__ b0a, const float* __restrict__ b0b,
    const float* __restrict__ b1a, const float* __restrict__ b1b,
    float* __restrict__ out, int M, int N, int K, int mode)
{
  __shared__ float As[64][17];
  __shared__ float Ws[64][17];
  const int tid = threadIdx.x;
  const int tn = tid & 15, tm = tid >> 4;
  const int n0 = blockIdx.x * 64, m0 = blockIdx.y * 64;
  const int srow = tid >> 2, sk = (tid & 3) * 4;
  float acc[4][4] = {};
  for (int k0 = 0; k0 < K; k0 += 16) {
    const int am = m0 + srow;
    #pragma unroll
    for (int q = 0; q < 4; ++q) {
      int k = k0 + sk + q;
      As[srow][sk + q] = (k < K) ? A[(size_t)am * lda + k] : 0.f;
    }
    const int wn = n0 + srow;
    const float* Wp = W0; int nn = wn;
    if (W1 != nullptr && wn >= Nhalf) { Wp = W1; nn = wn - Nhalf; }
    #pragma unroll
    for (int q = 0; q < 4; ++q) {
      int k = k0 + sk + q;
      Ws[srow][sk + q] = (wn < N && k < K) ? Wp[(size_t)nn * K + k] : 0.f;
    }
    __syncthreads();
    #pragma unroll
    for (int k = 0; k < 16; ++k) {
      float a[4], w[4];
      #pragma unroll
      for (int i = 0; i < 4; ++i) a[i] = As[tm*4+i][k];
      #pragma unroll
      for (int j = 0; j < 4; ++j) w[j] = Ws[tn*4+j][k];
      #pragma unroll
      for (int i = 0; i < 4; ++i)
        #pragma unroll
        for (int j = 0; j < 4; ++j) acc[i][j] += a[i]*w[j];
    }
    __syncthreads();
  }
  #pragma unroll
  for (int i = 0; i < 4; ++i) {
    #pragma unroll
    for (int j = 0; j < 4; ++j) {
      int m = m0 + tm*4 + i, n = n0 + tn*4 + j;
      if (n >= N) continue;
      float bias = 0.f;
      if (n < Nhalf) { if (b0a) bias += b0a[n]; if (b0b) bias += b0b[n]; }
      else { if (b1a) bias += b1a[n - Nhalf]; if (b1b) bias += b1b[n - Nhalf]; }
      float v = acc[i][j] + bias;
      if (mode == 2) {
        int dd = n >> 8, jj = n & 255, t = m >> 2, b = m & 3;
        int tq = dd ? (SEQ - 1 - t) : t;
        out[((size_t)(dd*SEQ + tq) * 256 + jj) * 4 + b] = v;
      } else {
        out[(size_t)m * N + n] = v;
      }
    }
  }
}

// W' = inprojW @ mprojW (512x23, row stride 23), b' = inprojW @ mprojB (512)
__global__ __launch_bounds__(256) void wcomb_k(
    const float* __restrict__ inprojW, const float* __restrict__ mprojW,
    const float* __restrict__ mprojB, float* __restrict__ wc,
    float* __restrict__ bvec)
{
  int idx = blockIdx.x * 256 + threadIdx.x;
  if (idx >= 512 * 24) return;
  int n = idx / 24, c = idx % 24;
  const float* wi = inprojW + (size_t)n * 128;
  float s = 0.f;
  if (c < 23) {
    for (int k = 0; k < 128; ++k) s += wi[k] * mprojW[k*23 + c];
    wc[n*23 + c] = s;
  } else {
    for (int k = 0; k < 128; ++k) s += wi[k] * mprojB[k];
    bvec[n] = s;
  }
}

// yc = (ys + xc*D) * silu(z)   (all [NM,256] contiguous)
__global__ __launch_bounds__(256) void ycomb_k(
    const float* __restrict__ z, const float* __restrict__ ys,
    const float* __restrict__ xc, const float* __restrict__ Dsk,
    float* __restrict__ yc)
{
  int idx = blockIdx.x * 256 + threadIdx.x;
  int d = idx & 255;
  float zz = z[idx];
  yc[idx] = (ys[idx] + xc[idx]*Dsk[d]) * zz * sigm(zz);
}

// ---------------------------------------------------------------------------
// FUSED launch: blocks 0-1 = LSTM recurrent scan (R7 body, bit-identical);
// blocks 2+ = one mamba pipeline stage (independent of the scan — its inputs
// were produced in a PREVIOUS launch, outputs consumed in a LATER one, so
// undefined intra-launch block order is safe).
//   stage 0: xi = x @ W'[0:256]^T + b'   (64x64-tile gemm rider)
//   stage 1: xc = silu(causal depthwise conv4(xi))        (elementwise)
//   stage 2: dbc = xc @ xprojW^T ; n0==0 blocks also dt = softplus(dbc[:,:8]@dtW^T+dtb)
//   stage 3: mamba selective scan (wave per (b,d))
// ---------------------------------------------------------------------------
#define HROW 80   // padded row stride (f16)
__global__ __launch_bounds__(512, 1) void fused_k(
    int stage,
    const float* __restrict__ G,    // [2][SEQ][256][4]
    const float* __restrict__ Whh,  // [2][256][64] (layer base)
    float* __restrict__ lout,       // [SEQ][4][128]
    const float* __restrict__ rA, int lda,
    const float* __restrict__ rW, const float* __restrict__ rbias,
    float* __restrict__ rout, int ldo, int N, int K,
    const float* __restrict__ dtW, const float* __restrict__ dtB,
    float* __restrict__ dtout,
    const float* __restrict__ mdbc, const float* __restrict__ mdtb,
    const float* __restrict__ mxc, const float* __restrict__ mAlog,
    float* __restrict__ mys)
{
  __shared__ _Float16 hb[2][16][HROW];    // scan: [buf][m=batch][k=n]
  __shared__ float glds[16][16][4];       // scan: [gate-tile][col][batch]
  __shared__ float As[64][17];            // gemm rider
  __shared__ float Ws[64][17];            // gemm rider
  __shared__ float dtl[64][8];            // stage-2 dt fusion

  const int tid = threadIdx.x;

  if (blockIdx.x < 2) {
    // ---------------- LSTM scan (identical to R7) ----------------
    const int dir = blockIdx.x;
    const int w = tid >> 6, lane = tid & 63;
    const int l15 = lane & 15, q = lane >> 4;

    for (int i = tid; i < 2*16*HROW; i += 512) ((_Float16*)hb)[i] = (_Float16)0.f;

    const float* Gd = G + (size_t)dir * SEQ * 1024;
    const float* Wd = Whh + dir * 256 * 64;
    const int T0 = w, T1 = w + 8;

    f16x8 bh[2][2];
    #pragma unroll
    for (int s = 0; s < 2; ++s) {
      const int j = ((s == 0) ? T0 : T1)*16 + l15;
      #pragma unroll
      for (int kt = 0; kt < 2; ++kt) {
        const float* src = Wd + j*64 + kt*32 + q*8;
        #pragma unroll
        for (int e = 0; e < 8; ++e) bh[s][kt][e] = (_Float16)src[e];
      }
    }

    float cc = 0.f;
    f4 gp0[2], gp1[2], gp2[2], gp3[2];

    auto loadG = [&](int t, f4* gv) {
      gv[0] = *(const f4*)(Gd + ((size_t)t*256 + T0*16 + l15)*4);
      gv[1] = *(const f4*)(Gd + ((size_t)t*256 + T1*16 + l15)*4);
    };
    loadG(0, gp0); loadG(1, gp1); loadG(2, gp2); loadG(3, gp3);
    __syncthreads();

    auto step = [&](int t, f4* gv) {
      const int p0 = t & 1, p1 = p0 ^ 1;
      f16x8 ah0 = *(const f16x8*)&hb[p0][l15][q*8];
      f16x8 ah1 = *(const f16x8*)&hb[p0][l15][q*8 + 32];
      f4 a0 = gv[0], a1 = gv[1];
      a0 = mfma16h(ah0, bh[0][0], a0); a0 = mfma16h(ah1, bh[0][1], a0);
      a1 = mfma16h(ah0, bh[1][0], a1); a1 = mfma16h(ah1, bh[1][1], a1);
      if (lane < 16) {
        *(f4*)&glds[T0][l15][0] = a0;
        *(f4*)&glds[T1][l15][0] = a1;
      }
      barrier_lds_only();
      if (w < 4) {
        float gi = glds[w     ][l15][q];
        float gf = glds[w +  4][l15][q];
        float gt = glds[w +  8][l15][q];
        float go = glds[w + 12][l15][q];
        cc = sigm(gf)*cc + sigm(gi)*tanhf_(gt);
        float hh = sigm(go)*tanhf_(cc);
        hb[p1][q][w*16 + l15] = (_Float16)hh;
        const int to = dir ? (SEQ-1 - t) : t;
        lout[((size_t)to*4 + q)*128 + dir*64 + w*16 + l15] = hh;
      }
      barrier_lds_only();
    };

    for (int t0 = 0; t0 < SEQ; t0 += 4) {
      step(t0+0, gp0); if (t0+4 < SEQ) loadG(t0+4, gp0);
      step(t0+1, gp1); if (t0+5 < SEQ) loadG(t0+5, gp1);
      step(t0+2, gp2); if (t0+6 < SEQ) loadG(t0+6, gp2);
      step(t0+3, gp3); if (t0+7 < SEQ) loadG(t0+7, gp3);
    }
    return;
  }

  // ---------------- mamba riders ----------------
  const int rb = blockIdx.x - 2;

  if (stage == 1) {       // conv4 + silu: xi [NM,256] -> xc [NM,256]
    int idx = rb*512 + tid;          // < NM*256
    int d = idx & 255, m = idx >> 8;
    int t = m >> 2, b = m & 3;
    float s = rbias[d];
    #pragma unroll
    for (int k = 0; k < 4; ++k) {
      int tt = t - 3 + k;
      if (tt >= 0) s += rA[(size_t)((tt*4 + b) << 8) + d] * rW[d*4 + k];
    }
    rout[idx] = s * sigm(s);
    return;
  }

  if (stage == 3) {       // selective scan, wave per (b,d)
    const int wid = rb*8 + (tid >> 6);
    const int lane = tid & 63;
    const int b = wid >> 8, d = wid & 255;
    const float Av = -__expf(mAlog[d*64 + lane]);
    const float* pB  = mdbc + (size_t)b*136 + 8 + lane;
    const float* pC  = mdbc + (size_t)b*136 + 72 + lane;
    const float* pdt = mdtb + (size_t)b*256 + d;
    const float* px  = mxc  + (size_t)b*256 + d;
    float* py = mys + (size_t)b*256 + d;
    float h = 0.f;
    float Bv = pB[0], Cv = pC[0], dtv = pdt[0], xv = px[0];
    #pragma unroll 2
    for (int t = 0; t < SEQ; ++t) {
      float Bn = 0.f, Cn = 0.f, dtn = 0.f, xn = 0.f;
      if (t + 1 < SEQ) {
        size_t od = (size_t)(t+1) * 544;
        size_t ox = (size_t)(t+1) * 1024;
        Bn = pB[od]; Cn = pC[od]; dtn = pdt[ox]; xn = px[ox];
      }
      float a = __expf(dtv * Av);
      h = a*h + (dtv*xv)*Bv;
      float p = h * Cv;
      #pragma unroll
      for (int mm = 1; mm < 64; mm <<= 1) p += __shfl_xor(p, mm, 64);
      if (lane == 0) py[(size_t)t * 1024] = p;
      Bv = Bn; Cv = Cn; dtv = dtn; xv = xn;
    }
    return;
  }

  // stage 0 / 2: 64x64-tile gemm rider (256 active threads of 512; all 512
  // participate in __syncthreads).  rout = rA @ rW^T (+rbias), rW stride = K.
  const int ntiles = (N + 63) >> 6;
  const int nt = rb % ntiles, mt = rb / ntiles;
  const int n0 = nt * 64, m0 = mt * 64;
  const bool act = tid < 256;
  const int tn = tid & 15, tm = (tid >> 4) & 15;
  const int srow = (tid >> 2) & 63, sk = (tid & 3) * 4;
  float acc[4][4] = {};
  for (int k0 = 0; k0 < K; k0 += 16) {
    if (act) {
      #pragma unroll
      for (int qq = 0; qq < 4; ++qq) {
        int k = k0 + sk + qq;
        As[srow][sk + qq] = (k < K) ? rA[(size_t)(m0 + srow) * lda + k] : 0.f;
        Ws[srow][sk + qq] = (n0 + srow < N && k < K) ? rW[(size_t)(n0 + srow) * K + k] : 0.f;
      }
    }
    __syncthreads();
    if (act) {
      #pragma unroll
      for (int k = 0; k < 16; ++k) {
        float a[4], w[4];
        #pragma unroll
        for (int i = 0; i < 4; ++i) a[i] = As[tm*4+i][k];
        #pragma unroll
        for (int j = 0; j < 4; ++j) w[j] = Ws[tn*4+j][k];
        #pragma unroll
        for (int i = 0; i < 4; ++i)
          #pragma unroll
          for (int j = 0; j < 4; ++j) acc[i][j] += a[i]*w[j];
      }
    }
    __syncthreads();
  }
  if (act) {
    #pragma unroll
    for (int i = 0; i < 4; ++i) {
      #pragma unroll
      for (int j = 0; j < 4; ++j) {
        int m = m0 + tm*4 + i, n = n0 + tn*4 + j;
        if (n >= N) continue;
        float v = acc[i][j] + (rbias ? rbias[n] : 0.f);
        rout[(size_t)m * ldo + n] = v;
        if (stage == 2 && nt == 0 && n < 8) dtl[tm*4+i][n] = v;
      }
    }
  }
  if (stage == 2 && nt == 0) {
    // dt = softplus(dbc[:, :8] @ dtW^T + dtB) for this block's 64 rows
    __syncthreads();
    for (int idx = tid; idx < 64*256; idx += 512) {
      int ml = idx >> 8, d = idx & 255;
      float s = dtB[d];
      #pragma unroll
      for (int r = 0; r < 8; ++r) s += dtl[ml][r] * dtW[d*8 + r];
      s = (s > 15.f) ? s : __logf(1.f + __expf(s));
      dtout[(size_t)(m0 + ml)*256 + d] = s;
    }
  }
}

// final LayerNorm(concat) -> gate -> mix.  One wave per (t,b).
__global__ __launch_bounds__(256) void combine_k(
    const float* __restrict__ lstm, const float* __restrict__ mam,
    const float* __restrict__ lnw, const float* __restrict__ lnb,
    const float* __restrict__ gW, const float* __restrict__ gb,
    float* __restrict__ out)
{
  const int pair = blockIdx.x * 4 + (threadIdx.x >> 6);
  const int lane = threadIdx.x & 63;
  const float2 lv = *(const float2*)(lstm + (size_t)pair*128 + lane*2);
  const float2 mv = *(const float2*)(mam  + (size_t)pair*128 + lane*2);
  float s  = lv.x + lv.y + mv.x + mv.y;
  float sq = lv.x*lv.x + lv.y*lv.y + mv.x*mv.x + mv.y*mv.y;
  #pragma unroll
  for (int mm = 1; mm < 64; mm <<= 1) { s += __shfl_xor(s, mm, 64); sq += __shfl_xor(sq, mm, 64); }
  const float mean = s * (1.f/256.f);
  const float var  = sq * (1.f/256.f) - mean*mean;
  const float inv  = rsqrtf(var + 1e-5f);
  const int c0 = lane*2, c2 = 128 + lane*2;
  float n0 = (lv.x-mean)*inv*lnw[c0]   + lnb[c0];
  float n1 = (lv.y-mean)*inv*lnw[c0+1] + lnb[c0+1];
  float n2 = (mv.x-mean)*inv*lnw[c2]   + lnb[c2];
  float n3 = (mv.y-mean)*inv*lnw[c2+1] + lnb[c2+1];
  float dot = n0*gW[c0] + n1*gW[c0+1] + n2*gW[c2] + n3*gW[c2+1];
  #pragma unroll
  for (int mm = 1; mm < 64; mm <<= 1) dot += __shfl_xor(dot, mm, 64);
  const float gate = sigm(dot + gb[0]);
  float2 o;
  o.x = gate*lv.x + (1.f-gate)*mv.x;
  o.y = gate*lv.y + (1.f-gate)*mv.y;
  *(float2*)(out + (size_t)pair*128 + lane*2) = o;
}

extern "C" void kernel_launch(void* const* d_in, const int* in_sizes, int n_in,
                              void* d_out, int out_size, void* d_ws, size_t ws_size,
                              hipStream_t stream)
{
  const float* x       = (const float*)d_in[0];
  const float* Wih0    = (const float*)d_in[1];
  const float* WihR    = (const float*)d_in[2];
  const float* Whh     = (const float*)d_in[3];
  const float* bih     = (const float*)d_in[4];
  const float* bhh     = (const float*)d_in[5];
  const float* mprojW  = (const float*)d_in[6];
  const float* mprojB  = (const float*)d_in[7];
  const float* inprojW = (const float*)d_in[8];
  const float* convw   = (const float*)d_in[9];
  const float* convb   = (const float*)d_in[10];
  const float* xprojW  = (const float*)d_in[11];
  const float* dtW     = (const float*)d_in[12];
  const float* dtB     = (const float*)d_in[13];
  const float* Alog    = (const float*)d_in[14];
  const float* Dskip   = (const float*)d_in[15];
  const float* outprojW= (const float*)d_in[16];
  const float* lnw     = (const float*)d_in[17];
  const float* lnb     = (const float*)d_in[18];
  const float* gWt     = (const float*)d_in[19];
  const float* gb      = (const float*)d_in[20];

  float* WS = (float*)d_ws;
  const size_t M1 = 1048576;
  // Workspace map (floats) — high water = 1 + 13.25 M1, same as R7-proven.
  float* mamba_out = WS;                    // [NM,128]
  float* P     = WS + M1;
  float* G     = P;                         // [2][SEQ][256][4] = 4M1 (lstm); tail: yc
  float* lstmA = P + 4*M1;                  // [NM,128]
  float* lstmB = P + 5*M1;                  // [NM,128]
  float* xi    = P + 6*M1;                  // [NM,256] (F0 out, F1 in)
  float* dtb   = P + 6*M1;                  // alias: [NM,256] (F2 out, F3 in)
  float* zbuf  = P + 6*M1;                  // alias: [NM,256] (tail)
  float* xc    = P + 8*M1;                  // [NM,256] (F1 out; F2, tail in)
  float* dbc   = P + 10*M1;                 // [NM,136] (F2 out, F3 in)
  float* wc    = P + 10*M1 + (size_t)NM*136;// [512][23]
  float* bvec  = wc + 512*23;               // [512]
  float* ysb   = P + 11*M1 + M1/4;          // [NM,256] (F3 out, tail in)
  float* yc    = G;                         // tail: [NM,256] (G dead after F3)
  float* outp  = (float*)d_out;

  dim3 blk(256);

  // pre: fold mproj into in_proj  (W' = inprojW@mprojW, b' = inprojW@mprojB)
  wcomb_k<<<48, blk, 0, stream>>>(inprojW, mprojW, mprojB, wc, bvec);

  // ---- LSTM layers with mamba stages riding the scan launches ----
  const float* lin = x;
  float* louts[4] = {lstmA, lstmB, lstmA, lstmB};
  for (int l = 0; l < 4; ++l) {
    const float* w0; const float* w1; int K;
    if (l == 0) { w0 = Wih0; w1 = Wih0 + 256*23; K = 23; }
    else {
      w0 = WihR + (size_t)((l-1)*2 + 0)*256*128;
      w1 = WihR + (size_t)((l-1)*2 + 1)*256*128;
      K = 128;
    }
    gemm_k<<<dim3(8,128), blk, 0, stream>>>(lin, K, w0, w1, 256,
        bih + (l*2+0)*256, bhh + (l*2+0)*256,
        bih + (l*2+1)*256, bhh + (l*2+1)*256,
        G, NM, 512, K, 2);
    const float* Wl = Whh + (size_t)l*2*256*64;
    if (l == 0) {        // rider: xi = x @ W'[0:256]^T + b'  (4 x 128 tiles)
      fused_k<<<2 + 512, dim3(512), 0, stream>>>(0, G, Wl, louts[l],
          x, 23, wc, bvec, xi, 256, 256, 23,
          nullptr, nullptr, nullptr, nullptr, nullptr, nullptr, nullptr, nullptr);
    } else if (l == 1) { // rider: conv+silu (NM*256 / 512 blocks)
      fused_k<<<2 + 4096, dim3(512), 0, stream>>>(1, G, Wl, louts[l],
          xi, 0, convw, convb, xc, 0, 0, 0,
          nullptr, nullptr, nullptr, nullptr, nullptr, nullptr, nullptr, nullptr);
    } else if (l == 2) { // rider: xproj (3 x 128 tiles) + fused dt
      fused_k<<<2 + 384, dim3(512), 0, stream>>>(2, G, Wl, louts[l],
          xc, 256, xprojW, nullptr, dbc, 136, 136, 256,
          dtW, dtB, dtb, nullptr, nullptr, nullptr, nullptr, nullptr);
    } else {             // rider: mamba selective scan (128 blocks x 8 waves)
      fused_k<<<2 + 128, dim3(512), 0, stream>>>(3, G, Wl, louts[l],
          nullptr, 0, nullptr, nullptr, nullptr, 0, 0, 0,
          nullptr, nullptr, nullptr, dbc, dtb, xc, Alog, ysb);
    }
    lin = louts[l];
  }

  // ---- tail: z-gemm, ycomb, out_proj, gate+mix ----
  gemm_k<<<dim3(4,128), blk, 0, stream>>>(x, 23, wc + 256*23, nullptr, 256,
      bvec + 256, nullptr, nullptr, nullptr, zbuf, NM, 256, 23, 0);
  ycomb_k<<<8192, blk, 0, stream>>>(zbuf, ysb, xc, Dskip, yc);
  gemm_k<<<dim3(2,128), blk, 0, stream>>>(yc, 256, outprojW, nullptr, 128,
      nullptr, nullptr, nullptr, nullptr, mamba_out, NM, 128, 256, 0);
  combine_k<<<2048, blk, 0, stream>>>(lstmB, mamba_out, lnw, lnb, gWt, gb, outp);
}

// Round 9
// 4620.696 us; speedup vs baseline: 1.6868x; 1.0075x over previous
//
#include <hip/hip_runtime.h>

#define SEQ   2048
#define NM    8192        // SEQ*BATCH

typedef __attribute__((ext_vector_type(4))) float f4;
typedef _Float16 f16x8 __attribute__((ext_vector_type(8)));

__device__ __forceinline__ float frcp(float x){ return __builtin_amdgcn_rcpf(x); }
__device__ __forceinline__ float sigm(float x){ return frcp(1.f + __expf(-x)); }
__device__ __forceinline__ float tanhf_(float x){ return 1.f - 2.f*frcp(__expf(2.f*x) + 1.f); }
__device__ __forceinline__ f4 mfma16h(f16x8 a, f16x8 b, f4 c){
  return __builtin_amdgcn_mfma_f32_16x16x32_f16(a, b, c, 0, 0, 0);
}
// LDS-only barrier: scan h/glds coherence needs lgkmcnt(0) only; G prefetch
// global loads stay in flight across the barrier.
__device__ __forceinline__ void barrier_lds_only(){
  asm volatile("s_waitcnt lgkmcnt(0)\n\ts_barrier" ::: "memory");
}

// ---------------------------------------------------------------------------
// Generic tiled GEMM (256 thr): out = A[M,K] @ W[N,K]^T (+bias), epilogues.
// mode 0: plain   mode 2: LSTM-G store [dir][t][j][b], time-reversed for dir1.
// ---------------------------------------------------------------------------
__global__ __launch_bounds__(256) void gemm_k(
    const float* __restrict__ A, int lda,
    const float* __restrict__ W0, const float* __restrict__ W1, int Nhalf,
    const float* __restrict__ b0a, const float* __restrict__ b0b,
    const float* __restrict__ b1a, const float* __restrict__ b1b,
    float* __restrict__ out, int M, int N, int K, int mode)
{
  __shared__ float As[64][17];
  __shared__ float Ws[64][17];
  const int tid = threadIdx.x;
  const int tn = tid & 15, tm = tid >> 4;
  const int n0 = blockIdx.x * 64, m0 = blockIdx.y * 64;
  const int srow = tid >> 2, sk = (tid & 3) * 4;
  float acc[4][4] = {};
  for (int k0 = 0; k0 < K; k0 += 16) {
    const int am = m0 + srow;
    #pragma unroll
    for (int q = 0; q < 4; ++q) {
      int k = k0 + sk + q;
      As[srow][sk + q] = (k < K) ? A[(size_t)am * lda + k] : 0.f;
    }
    const int wn = n0 + srow;
    const float* Wp = W0; int nn = wn;
    if (W1 != nullptr && wn >= Nhalf) { Wp = W1; nn = wn - Nhalf; }
    #pragma unroll
    for (int q = 0; q < 4; ++q) {
      int k = k0 + sk + q;
      Ws[srow][sk + q] = (wn < N && k < K) ? Wp[(size_t)nn * K + k] : 0.f;
    }
    __syncthreads();
    #pragma unroll
    for (int k = 0; k < 16; ++k) {
      float a[4], w[4];
      #pragma unroll
      for (int i = 0; i < 4; ++i) a[i] = As[tm*4+i][k];
      #pragma unroll
      for (int j = 0; j < 4; ++j) w[j] = Ws[tn*4+j][k];
      #pragma unroll
      for (int i = 0; i < 4; ++i)
        #pragma unroll
        for (int j = 0; j < 4; ++j) acc[i][j] += a[i]*w[j];
    }
    __syncthreads();
  }
  #pragma unroll
  for (int i = 0; i < 4; ++i) {
    #pragma unroll
    for (int j = 0; j < 4; ++j) {
      int m = m0 + tm*4 + i, n = n0 + tn*4 + j;
      if (n >= N) continue;
      float bias = 0.f;
      if (n < Nhalf) { if (b0a) bias += b0a[n]; if (b0b) bias += b0b[n]; }
      else { if (b1a) bias += b1a[n - Nhalf]; if (b1b) bias += b1b[n - Nhalf]; }
      float v = acc[i][j] + bias;
      if (mode == 2) {
        int dd = n >> 8, jj = n & 255, t = m >> 2, b = m & 3;
        int tq = dd ? (SEQ - 1 - t) : t;
        out[((size_t)(dd*SEQ + tq) * 256 + jj) * 4 + b] = v;
      } else {
        out[(size_t)m * N + n] = v;
      }
    }
  }
}

// W' = inprojW @ mprojW (512x23, row stride 23), b' = inprojW @ mprojB (512)
__global__ __launch_bounds__(256) void wcomb_k(
    const float* __restrict__ inprojW, const float* __restrict__ mprojW,
    const float* __restrict__ mprojB, float* __restrict__ wc,
    float* __restrict__ bvec)
{
  int idx = blockIdx.x * 256 + threadIdx.x;
  if (idx >= 512 * 24) return;
  int n = idx / 24, c = idx % 24;
  const float* wi = inprojW + (size_t)n * 128;
  float s = 0.f;
  if (c < 23) {
    for (int k = 0; k < 128; ++k) s += wi[k] * mprojW[k*23 + c];
    wc[n*23 + c] = s;
  } else {
    for (int k = 0; k < 128; ++k) s += wi[k] * mprojB[k];
    bvec[n] = s;
  }
}

// yc = (ys + xc*D) * silu(z)   (all [NM,256] contiguous)
__global__ __launch_bounds__(256) void ycomb_k(
    const float* __restrict__ z, const float* __restrict__ ys,
    const float* __restrict__ xc, const float* __restrict__ Dsk,
    float* __restrict__ yc)
{
  int idx = blockIdx.x * 256 + threadIdx.x;
  int d = idx & 255;
  float zz = z[idx];
  yc[idx] = (ys[idx] + xc[idx]*Dsk[d]) * zz * sigm(zz);
}

// ---------------------------------------------------------------------------
// FUSED launch (256 thr): blocks 0-1 = LSTM scan; blocks 2+ = mamba stage.
// SCAN (this round's change): 4 waves, R2 tile assignment — wave w owns gate
// tiles {w, w+4, w+8, w+12} = all 4 gates for hid cols 16w..16w+15.  Gate
// redistribution is INTRA-WAVE (per-wave glds, write lane<16 -> read all
// lanes; compiler lgkmcnt only, no barrier — HW-proven in R2), combined with
// R7's single-pass f16 MFMA (8 MFMAs/wave, 2-deep chains).  ONE barrier per
// step (publish h), vs R7's two.  Act on all 64 lanes/wave (no transcendental
// concentration — R5 lesson).
// Riders: stage 0 xi-gemm; 1 conv+silu; 2 xproj+dt; 3 selective scan.
// ---------------------------------------------------------------------------
#define HROW 80   // padded row stride (f16)
__global__ __launch_bounds__(256, 1) void fused_k(
    int stage,
    const float* __restrict__ G,    // [2][SEQ][256][4]
    const float* __restrict__ Whh,  // [2][256][64] (layer base)
    float* __restrict__ lout,       // [SEQ][4][128]
    const float* __restrict__ rA, int lda,
    const float* __restrict__ rW, const float* __restrict__ rbias,
    float* __restrict__ rout, int ldo, int N, int K,
    const float* __restrict__ dtW, const float* __restrict__ dtB,
    float* __restrict__ dtout,
    const float* __restrict__ mdbc, const float* __restrict__ mdtb,
    const float* __restrict__ mxc, const float* __restrict__ mAlog,
    float* __restrict__ mys)
{
  __shared__ _Float16 hb[2][16][HROW];    // scan: [buf][m=batch][k=col]
  __shared__ float glds[4][4][16][4];     // scan: [wave][gate][col][batch]
  __shared__ float As[64][17];            // gemm rider
  __shared__ float Ws[64][17];            // gemm rider
  __shared__ float dtl[64][8];            // stage-2 dt fusion

  const int tid = threadIdx.x;

  if (blockIdx.x < 2) {
    // ---------------- LSTM scan ----------------
    const int dir = blockIdx.x;
    const int w = tid >> 6, lane = tid & 63;   // w in 0..3
    const int l15 = lane & 15, q = lane >> 4;

    for (int i = tid; i < 2*16*HROW; i += 256) ((_Float16*)hb)[i] = (_Float16)0.f;

    const float* Gd = G + (size_t)dir * SEQ * 1024;
    const float* Wd = Whh + dir * 256 * 64;

    // B fragments: wave w owns gate tiles {4g+w}, g=0..3 (gate i,f,g,o)
    f16x8 bh[4][2];
    #pragma unroll
    for (int g = 0; g < 4; ++g) {
      const int j = (g*4 + w)*16 + l15;
      #pragma unroll
      for (int kt = 0; kt < 2; ++kt) {
        const float* src = Wd + j*64 + kt*32 + q*8;
        #pragma unroll
        for (int e = 0; e < 8; ++e) bh[g][kt][e] = (_Float16)src[e];
      }
    }

    float cc = 0.f;                 // cell state: lane = (batch q, col 16w+l15)
    f4 gp0[4], gp1[4], gp2[4], gp3[4];

    auto loadG = [&](int t, f4* gv) {
      #pragma unroll
      for (int g = 0; g < 4; ++g) {
        const int j = (g*4 + w)*16 + l15;
        gv[g] = *(const f4*)(Gd + ((size_t)t * 256 + j) * 4);
      }
    };
    loadG(0, gp0); loadG(1, gp1); loadG(2, gp2); loadG(3, gp3);
    __syncthreads();

    auto step = [&](int t, f4* gv) {
      const int p0 = t & 1, p1 = p0 ^ 1;
      f16x8 ah0 = *(const f16x8*)&hb[p0][l15][q*8];
      f16x8 ah1 = *(const f16x8*)&hb[p0][l15][q*8 + 32];
      f4 a0 = gv[0], a1 = gv[1], a2 = gv[2], a3 = gv[3];
      a0 = mfma16h(ah0, bh[0][0], a0); a0 = mfma16h(ah1, bh[0][1], a0);
      a1 = mfma16h(ah0, bh[1][0], a1); a1 = mfma16h(ah1, bh[1][1], a1);
      a2 = mfma16h(ah0, bh[2][0], a2); a2 = mfma16h(ah1, bh[2][1], a2);
      a3 = mfma16h(ah0, bh[3][0], a3); a3 = mfma16h(ah1, bh[3][1], a3);
      if (lane < 16) {
        *(f4*)&glds[w][0][l15][0] = a0;
        *(f4*)&glds[w][1][l15][0] = a1;
        *(f4*)&glds[w][2][l15][0] = a2;
        *(f4*)&glds[w][3][l15][0] = a3;
      }
      // intra-wave write->read: compiler lgkmcnt, no barrier (R2-proven)
      float gi = glds[w][0][l15][q];
      float gf = glds[w][1][l15][q];
      float gt = glds[w][2][l15][q];
      float go = glds[w][3][l15][q];
      cc = sigm(gf)*cc + sigm(gi)*tanhf_(gt);
      float hh = sigm(go)*tanhf_(cc);
      hb[p1][q][w*16 + l15] = (_Float16)hh;
      const int to = dir ? (SEQ-1 - t) : t;
      lout[((size_t)to*4 + q)*128 + dir*64 + w*16 + l15] = hh;
      barrier_lds_only();           // single barrier: publish h
    };

    for (int t0 = 0; t0 < SEQ; t0 += 4) {
      step(t0+0, gp0); if (t0+4 < SEQ) loadG(t0+4, gp0);
      step(t0+1, gp1); if (t0+5 < SEQ) loadG(t0+5, gp1);
      step(t0+2, gp2); if (t0+6 < SEQ) loadG(t0+6, gp2);
      step(t0+3, gp3); if (t0+7 < SEQ) loadG(t0+7, gp3);
    }
    return;
  }

  // ---------------- mamba riders ----------------
  const int rb = blockIdx.x - 2;

  if (stage == 1) {       // conv4 + silu: xi [NM,256] -> xc [NM,256]
    int idx = rb*256 + tid;          // < NM*256
    int d = idx & 255, m = idx >> 8;
    int t = m >> 2, b = m & 3;
    float s = rbias[d];
    #pragma unroll
    for (int k = 0; k < 4; ++k) {
      int tt = t - 3 + k;
      if (tt >= 0) s += rA[(size_t)((tt*4 + b) << 8) + d] * rW[d*4 + k];
    }
    rout[idx] = s * sigm(s);
    return;
  }

  if (stage == 3) {       // selective scan, wave per (b,d)
    const int wid = rb*4 + (tid >> 6);
    const int lane = tid & 63;
    const int b = wid >> 8, d = wid & 255;
    const float Av = -__expf(mAlog[d*64 + lane]);
    const float* pB  = mdbc + (size_t)b*136 + 8 + lane;
    const float* pC  = mdbc + (size_t)b*136 + 72 + lane;
    const float* pdt = mdtb + (size_t)b*256 + d;
    const float* px  = mxc  + (size_t)b*256 + d;
    float* py = mys + (size_t)b*256 + d;
    float h = 0.f;
    float Bv = pB[0], Cv = pC[0], dtv = pdt[0], xv = px[0];
    #pragma unroll 2
    for (int t = 0; t < SEQ; ++t) {
      float Bn = 0.f, Cn = 0.f, dtn = 0.f, xn = 0.f;
      if (t + 1 < SEQ) {
        size_t od = (size_t)(t+1) * 544;
        size_t ox = (size_t)(t+1) * 1024;
        Bn = pB[od]; Cn = pC[od]; dtn = pdt[ox]; xn = px[ox];
      }
      float a = __expf(dtv * Av);
      h = a*h + (dtv*xv)*Bv;
      float p = h * Cv;
      #pragma unroll
      for (int mm = 1; mm < 64; mm <<= 1) p += __shfl_xor(p, mm, 64);
      if (lane == 0) py[(size_t)t * 1024] = p;
      Bv = Bn; Cv = Cn; dtv = dtn; xv = xn;
    }
    return;
  }

  // stage 0 / 2: 64x64-tile gemm rider (256 threads).
  // rout = rA @ rW^T (+rbias), rW row stride = K.
  const int ntiles = (N + 63) >> 6;
  const int nt = rb % ntiles, mt = rb / ntiles;
  const int n0 = nt * 64, m0 = mt * 64;
  const int tn = tid & 15, tm = tid >> 4;
  const int srow = tid >> 2, sk = (tid & 3) * 4;
  float acc[4][4] = {};
  for (int k0 = 0; k0 < K; k0 += 16) {
    #pragma unroll
    for (int qq = 0; qq < 4; ++qq) {
      int k = k0 + sk + qq;
      As[srow][sk + qq] = (k < K) ? rA[(size_t)(m0 + srow) * lda + k] : 0.f;
      Ws[srow][sk + qq] = (n0 + srow < N && k < K) ? rW[(size_t)(n0 + srow) * K + k] : 0.f;
    }
    __syncthreads();
    #pragma unroll
    for (int k = 0; k < 16; ++k) {
      float a[4], w[4];
      #pragma unroll
      for (int i = 0; i < 4; ++i) a[i] = As[tm*4+i][k];
      #pragma unroll
      for (int j = 0; j < 4; ++j) w[j] = Ws[tn*4+j][k];
      #pragma unroll
      for (int i = 0; i < 4; ++i)
        #pragma unroll
        for (int j = 0; j < 4; ++j) acc[i][j] += a[i]*w[j];
    }
    __syncthreads();
  }
  #pragma unroll
  for (int i = 0; i < 4; ++i) {
    #pragma unroll
    for (int j = 0; j < 4; ++j) {
      int m = m0 + tm*4 + i, n = n0 + tn*4 + j;
      if (n >= N) continue;
      float v = acc[i][j] + (rbias ? rbias[n] : 0.f);
      rout[(size_t)m * ldo + n] = v;
      if (stage == 2 && nt == 0 && n < 8) dtl[tm*4+i][n] = v;
    }
  }
  if (stage == 2 && nt == 0) {
    // dt = softplus(dbc[:, :8] @ dtW^T + dtB) for this block's 64 rows
    __syncthreads();
    for (int idx = tid; idx < 64*256; idx += 256) {
      int ml = idx >> 8, d = idx & 255;
      float s = dtB[d];
      #pragma unroll
      for (int r = 0; r < 8; ++r) s += dtl[ml][r] * dtW[d*8 + r];
      s = (s > 15.f) ? s : __logf(1.f + __expf(s));
      dtout[(size_t)(m0 + ml)*256 + d] = s;
    }
  }
}

// final LayerNorm(concat) -> gate -> mix.  One wave per (t,b).
__global__ __launch_bounds__(256) void combine_k(
    const float* __restrict__ lstm, const float* __restrict__ mam,
    const float* __restrict__ lnw, const float* __restrict__ lnb,
    const float* __restrict__ gW, const float* __restrict__ gb,
    float* __restrict__ out)
{
  const int pair = blockIdx.x * 4 + (threadIdx.x >> 6);
  const int lane = threadIdx.x & 63;
  const float2 lv = *(const float2*)(lstm + (size_t)pair*128 + lane*2);
  const float2 mv = *(const float2*)(mam  + (size_t)pair*128 + lane*2);
  float s  = lv.x + lv.y + mv.x + mv.y;
  float sq = lv.x*lv.x + lv.y*lv.y + mv.x*mv.x + mv.y*mv.y;
  #pragma unroll
  for (int mm = 1; mm < 64; mm <<= 1) { s += __shfl_xor(s, mm, 64); sq += __shfl_xor(sq, mm, 64); }
  const float mean = s * (1.f/256.f);
  const float var  = sq * (1.f/256.f) - mean*mean;
  const float inv  = rsqrtf(var + 1e-5f);
  const int c0 = lane*2, c2 = 128 + lane*2;
  float n0 = (lv.x-mean)*inv*lnw[c0]   + lnb[c0];
  float n1 = (lv.y-mean)*inv*lnw[c0+1] + lnb[c0+1];
  float n2 = (mv.x-mean)*inv*lnw[c2]   + lnb[c2];
  float n3 = (mv.y-mean)*inv*lnw[c2+1] + lnb[c2+1];
  float dot = n0*gW[c0] + n1*gW[c0+1] + n2*gW[c2] + n3*gW[c2+1];
  #pragma unroll
  for (int mm = 1; mm < 64; mm <<= 1) dot += __shfl_xor(dot, mm, 64);
  const float gate = sigm(dot + gb[0]);
  float2 o;
  o.x = gate*lv.x + (1.f-gate)*mv.x;
  o.y = gate*lv.y + (1.f-gate)*mv.y;
  *(float2*)(out + (size_t)pair*128 + lane*2) = o;
}

extern "C" void kernel_launch(void* const* d_in, const int* in_sizes, int n_in,
                              void* d_out, int out_size, void* d_ws, size_t ws_size,
                              hipStream_t stream)
{
  const float* x       = (const float*)d_in[0];
  const float* Wih0    = (const float*)d_in[1];
  const float* WihR    = (const float*)d_in[2];
  const float* Whh     = (const float*)d_in[3];
  const float* bih     = (const float*)d_in[4];
  const float* bhh     = (const float*)d_in[5];
  const float* mprojW  = (const float*)d_in[6];
  const float* mprojB  = (const float*)d_in[7];
  const float* inprojW = (const float*)d_in[8];
  const float* convw   = (const float*)d_in[9];
  const float* convb   = (const float*)d_in[10];
  const float* xprojW  = (const float*)d_in[11];
  const float* dtW     = (const float*)d_in[12];
  const float* dtB     = (const float*)d_in[13];
  const float* Alog    = (const float*)d_in[14];
  const float* Dskip   = (const float*)d_in[15];
  const float* outprojW= (const float*)d_in[16];
  const float* lnw     = (const float*)d_in[17];
  const float* lnb     = (const float*)d_in[18];
  const float* gWt     = (const float*)d_in[19];
  const float* gb      = (const float*)d_in[20];

  float* WS = (float*)d_ws;
  const size_t M1 = 1048576;
  // Workspace map (floats) — high water = 1 + 13.25 M1 (R8-proven).
  float* mamba_out = WS;                    // [NM,128]
  float* P     = WS + M1;
  float* G     = P;                         // [2][SEQ][256][4] = 4M1 (lstm); tail: yc
  float* lstmA = P + 4*M1;                  // [NM,128]
  float* lstmB = P + 5*M1;                  // [NM,128]
  float* xi    = P + 6*M1;                  // [NM,256] (F0 out, F1 in)
  float* dtb   = P + 6*M1;                  // alias: [NM,256] (F2 out, F3 in)
  float* zbuf  = P + 6*M1;                  // alias: [NM,256] (tail)
  float* xc    = P + 8*M1;                  // [NM,256] (F1 out; F2, tail in)
  float* dbc   = P + 10*M1;                 // [NM,136] (F2 out, F3 in)
  float* wc    = P + 10*M1 + (size_t)NM*136;// [512][23]
  float* bvec  = wc + 512*23;               // [512]
  float* ysb   = P + 11*M1 + M1/4;          // [NM,256] (F3 out, tail in)
  float* yc    = G;                         // tail: [NM,256] (G dead after F3)
  float* outp  = (float*)d_out;

  dim3 blk(256);

  // pre: fold mproj into in_proj  (W' = inprojW@mprojW, b' = inprojW@mprojB)
  wcomb_k<<<48, blk, 0, stream>>>(inprojW, mprojW, mprojB, wc, bvec);

  // ---- LSTM layers with mamba stages riding the scan launches ----
  const float* lin = x;
  float* louts[4] = {lstmA, lstmB, lstmA, lstmB};
  for (int l = 0; l < 4; ++l) {
    const float* w0; const float* w1; int K;
    if (l == 0) { w0 = Wih0; w1 = Wih0 + 256*23; K = 23; }
    else {
      w0 = WihR + (size_t)((l-1)*2 + 0)*256*128;
      w1 = WihR + (size_t)((l-1)*2 + 1)*256*128;
      K = 128;
    }
    gemm_k<<<dim3(8,128), blk, 0, stream>>>(lin, K, w0, w1, 256,
        bih + (l*2+0)*256, bhh + (l*2+0)*256,
        bih + (l*2+1)*256, bhh + (l*2+1)*256,
        G, NM, 512, K, 2);
    const float* Wl = Whh + (size_t)l*2*256*64;
    if (l == 0) {        // rider: xi = x @ W'[0:256]^T + b'  (4 x 128 tiles)
      fused_k<<<2 + 512, blk, 0, stream>>>(0, G, Wl, louts[l],
          x, 23, wc, bvec, xi, 256, 256, 23,
          nullptr, nullptr, nullptr, nullptr, nullptr, nullptr, nullptr, nullptr);
    } else if (l == 1) { // rider: conv+silu (NM*256 / 256 blocks)
      fused_k<<<2 + 8192, blk, 0, stream>>>(1, G, Wl, louts[l],
          xi, 0, convw, convb, xc, 0, 0, 0,
          nullptr, nullptr, nullptr, nullptr, nullptr, nullptr, nullptr, nullptr);
    } else if (l == 2) { // rider: xproj (3 x 128 tiles) + fused dt
      fused_k<<<2 + 384, blk, 0, stream>>>(2, G, Wl, louts[l],
          xc, 256, xprojW, nullptr, dbc, 136, 136, 256,
          dtW, dtB, dtb, nullptr, nullptr, nullptr, nullptr, nullptr);
    } else {             // rider: mamba selective scan (256 blocks x 4 waves)
      fused_k<<<2 + 256, blk, 0, stream>>>(3, G, Wl, louts[l],
          nullptr, 0, nullptr, nullptr, nullptr, 0, 0, 0,
          nullptr, nullptr, nullptr, dbc, dtb, xc, Alog, ysb);
    }
    lin = louts[l];
  }

  // ---- tail: z-gemm, ycomb, out_proj, gate+mix ----
  gemm_k<<<dim3(4,128), blk, 0, stream>>>(x, 23, wc + 256*23, nullptr, 256,
      bvec + 256, nullptr, nullptr, nullptr, zbuf, NM, 256, 23, 0);
  ycomb_k<<<8192, blk, 0, stream>>>(zbuf, ysb, xc, Dskip, yc);
  gemm_k<<<dim3(2,128), blk, 0, stream>>>(yc, 256, outprojW, nullptr, 128,
      nullptr, nullptr, nullptr, nullptr, mamba_out, NM, 128, 256, 0);
  combine_k<<<2048, blk, 0, stream>>>(lstmB, mamba_out, lnw, lnb, gWt, gb, outp);
}